// Round 8
// baseline (720.531 us; speedup 1.0000x reference)
//
#include <hip/hip_runtime.h>

typedef __bf16 bf16;
typedef __attribute__((ext_vector_type(8))) __bf16 bf16x8;
typedef __attribute__((ext_vector_type(4))) float floatx4;

#define TOK 2048
#define DD  1024
#define NE  8
#define SMAX 24   // worklist slots (BM=256): <=15 routed + 8 shared, padded to %8==0

#define MFMA16(A,B,C) __builtin_amdgcn_mfma_f32_16x16x32_bf16(A,B,C,0,0,0)

__device__ __forceinline__ void load_lds16(const bf16* g, bf16* l) {
  __builtin_amdgcn_global_load_lds(
      (const __attribute__((address_space(1))) void*)g,
      (__attribute__((address_space(3))) void*)l, 16, 0, 0);
}

// fine-grained barrier: wait only the OLDEST outstanding loads, keep N in flight
#define WBAR(N) asm volatile("s_waitcnt vmcnt(" #N ")\n\ts_barrier" ::: "memory")
#define BARO    asm volatile("s_barrier" ::: "memory")

__device__ __forceinline__ uint4 pack_bf8(float4 a, float4 b) {
  union { bf16 h[8]; uint4 u; } p;
  p.h[0] = (bf16)a.x; p.h[1] = (bf16)a.y; p.h[2] = (bf16)a.z; p.h[3] = (bf16)a.w;
  p.h[4] = (bf16)b.x; p.h[5] = (bf16)b.y; p.h[6] = (bf16)b.z; p.h[7] = (bf16)b.w;
  return p.u;
}

// ---------------- prep: gate + x->bf16 + weight convert + w2col0 + fused ROUTE ----------------
// Gate blocks [0,2048): gate + x->bf16 + ss zero + h[:,0]=0. Each gate block release-fences
// and bumps `done`; the launch's last finisher (old%2048==2047 — exactly one per launch,
// no zeroing needed, robust to garbage init) acquire-fences and runs the route body inline.
// Convert blocks: 2 rows/block, 8 floats/thread (16B stores — r0-proven width).
#define NCVT (8*2046 + 2046 + 8*1023 + 1023)
#define NCVT2 ((NCVT + 1) / 2)
#define GATEB TOK
__global__ __launch_bounds__(256) void prep_kernel(
    const float* __restrict__ x, const float* __restrict__ gate_w,
    const float* __restrict__ gate_b,
    const float* __restrict__ W1, const float* __restrict__ W3,
    const float* __restrict__ W2, const float* __restrict__ Ws1,
    const float* __restrict__ Ws3, const float* __restrict__ Ws2,
    bf16* __restrict__ x_bf, int* __restrict__ eidx, float* __restrict__ ewgt,
    float* __restrict__ ss,
    bf16* __restrict__ w13, bf16* __restrict__ ws13,
    bf16* __restrict__ w2b, bf16* __restrict__ ws2b,
    float* __restrict__ w2c0_r, float* __restrict__ w2c0_s,
    bf16* __restrict__ h_r, bf16* __restrict__ h_s,
    unsigned* __restrict__ done,
    int* __restrict__ perm, int* __restrict__ pos_of,
    int4* __restrict__ wl, int* __restrict__ wl_n)
{
  const int bid = blockIdx.x, tid = threadIdx.x;

  if (bid >= GATEB) {
    // ---- weight convert: 2 rows per block, 8 floats/thread, uint4 stores ----
    const int j = bid - GATEB;
    const int r = j * 2 + (tid >> 7);
    if (r < NCVT) {
      const int tid2 = tid & 127;
      const float* src; bf16* dst;
      float* c0dst = nullptr;
      if (r < 8 * 2046) {
        const int e = r / 2046, q = r % 2046;
        src = ((q & 1) ? W3 : W1) + ((size_t)e * 1023 + (q >> 1)) * 1024;
        dst = w13 + (size_t)r * 1024;
      } else if (r < 8 * 2046 + 2046) {
        const int q = r - 8 * 2046;
        src = ((q & 1) ? Ws3 : Ws1) + (size_t)(q >> 1) * 1024;
        dst = ws13 + (size_t)q * 1024;
      } else if (r < 8 * 2046 + 2046 + 8 * 1023) {
        const int q = r - (8 * 2046 + 2046);
        src = W2 + (size_t)q * 1024;
        dst = w2b + (size_t)q * 1024;
        c0dst = w2c0_r + (size_t)(q / 1023) * 1024 + (q % 1023);  // padded [E][1024]
      } else {
        const int q = r - (8 * 2046 + 2046 + 8 * 1023);
        src = Ws2 + (size_t)q * 1024;
        dst = ws2b + (size_t)q * 1024;
        c0dst = w2c0_s + q;
      }
      const float4 f0 = ((const float4*)src)[tid2 * 2];
      const float4 f1 = ((const float4*)src)[tid2 * 2 + 1];
      if (tid2 == 0 && c0dst) *c0dst = f0.x;   // W2[:,0] (time-lift column)
      ((uint4*)dst)[tid2] = pack_bf8(f0, f1);
    }
    return;
  }

  // ---- gate + x->bf16 + ss zero (ss_r, ss_z) + h[:,0]=0 ----
  const int t = bid;
  if (tid < 2) ss[tid * TOK + t] = 0.f;
  if (tid == 2) h_r[(size_t)t * 1024] = (bf16)0.f;
  if (tid == 3) h_s[(size_t)t * 1024] = (bf16)0.f;
  const float4 v = ((const float4*)(x + (size_t)t * DD))[tid];
  union { bf16 h[4]; uint2 u; } pk;
  pk.h[0] = (bf16)v.x; pk.h[1] = (bf16)v.y; pk.h[2] = (bf16)v.z; pk.h[3] = (bf16)v.w;
  ((uint2*)(x_bf + (size_t)t * DD))[tid] = pk.u;

  float acc[NE];
#pragma unroll
  for (int e = 0; e < NE; ++e) acc[e] = 0.f;
  const float vv[4] = {v.x, v.y, v.z, v.w};
#pragma unroll
  for (int i = 0; i < 4; ++i) {
    const int d = tid * 4 + i;
    if (d >= 1) {
#pragma unroll
      for (int e = 0; e < NE; ++e) acc[e] += vv[i] * gate_w[e * (DD - 1) + d - 1];
    }
  }
#pragma unroll
  for (int off = 32; off > 0; off >>= 1) {
#pragma unroll
    for (int e = 0; e < NE; ++e) acc[e] += __shfl_down(acc[e], off);
  }
  __shared__ float red[4][NE];
  __shared__ int iswin;
  const int wid = tid >> 6, lane = tid & 63;
  if (lane == 0) {
#pragma unroll
    for (int e = 0; e < NE; ++e) red[wid][e] = acc[e];
  }
  __syncthreads();
  if (tid == 0) {
    float lg[NE];
#pragma unroll
    for (int e = 0; e < NE; ++e) lg[e] = red[0][e] + red[1][e] + red[2][e] + red[3][e];
    float m = lg[0];
    for (int e = 1; e < NE; ++e) m = fmaxf(m, lg[e]);
    float ex[NE], s = 0.f;
    for (int e = 0; e < NE; ++e) { ex[e] = expf(lg[e] - m); s += ex[e]; }
    const float inv = 1.f / s;
    int best = 0; float bb = ex[0] * inv + gate_b[0];
    for (int e = 1; e < NE; ++e) {
      const float b = ex[e] * inv + gate_b[e];
      if (b > bb) { bb = b; best = e; }
    }
    eidx[t] = best;
    ewgt[t] = ex[best] * inv;
    __threadfence();                                  // release: eidx/ewgt visible
    const unsigned old = atomicAdd(done, 1u);
    iswin = ((old & (unsigned)(GATEB - 1)) == (unsigned)(GATEB - 1)) ? 1 : 0;
  }
  __syncthreads();
  if (!iswin) return;

  // ---- ROUTE (runs in the last-finishing gate block; all 2048 eidx visible) ----
  __threadfence();                                    // acquire
  __shared__ int cnt[NE], off[NE], bas[NE + 1];
  if (tid < NE) cnt[tid] = 0;
  __syncthreads();
  for (int tt = tid; tt < TOK; tt += 256) atomicAdd(&cnt[eidx[tt]], 1);
  __syncthreads();
  if (tid == 0) {
    int run = 0;
    for (int e = 0; e < NE; ++e) { bas[e] = run; off[e] = run; run += cnt[e]; }
    bas[NE] = run;
    int n = 0;
    for (int e = 0; e < NE; ++e)
      for (int r0 = 0; r0 < cnt[e]; r0 += 256) {
        int rows = cnt[e] - r0; if (rows > 256) rows = 256;
        wl[n++] = make_int4(bas[e] + r0, rows, e, 0);
      }
    for (int r0 = 0; r0 < TOK; r0 += 256) wl[n++] = make_int4(r0, 256, NE, 0);
    *wl_n = n;
  }
  __syncthreads();
  for (int tt = tid; tt < TOK; tt += 256) {
    const int e = eidx[tt];
    const int p = atomicAdd(&off[e], 1);
    perm[p] = tt;
    pos_of[tt] = p;
  }
}

// ---------------- mlp1: BM=256 x BN=256 x BK=64, 16 waves, dbuf + vmcnt(4) ----------------
// UNCHANGED control (measured 44us, 0 conflicts, best per-CU staging rate).
__global__ __launch_bounds__(1024) void mlp1_kernel(
    const bf16* __restrict__ x_bf, const bf16* __restrict__ w13,
    const bf16* __restrict__ ws13,
    const int* __restrict__ perm, const int4* __restrict__ wl,
    const int* __restrict__ wl_n,
    bf16* __restrict__ h_r, bf16* __restrict__ h_s,
    float* __restrict__ ss_r, float* __restrict__ ss_z)
{
  const int bid = blockIdx.x;
  const int slot = bid % SMAX, nt = bid / SMAX;   // nt in 0..7
  if (slot >= *wl_n) return;
  const int4 wle = wl[slot];
  const int mbase = wle.x, rows = wle.y, eid = wle.z;
  const int tid = threadIdx.x;
  const bool routed = (eid < NE);
  const bf16* bmat = routed ? w13 + (size_t)eid * 2046 * 1024 : ws13;
  bf16* hbuf  = routed ? h_r : h_s;
  float* ssbuf = routed ? ss_r : ss_z;

  extern __shared__ __align__(16) bf16 smem[];
  bf16* const Asb[2] = {smem, smem + 16384};            // 256x64 each
  bf16* const Bsb[2] = {smem + 32768, smem + 49152};    // 256x64 each
  __shared__ int toks[256];
  if (tid < 256) {
    int r = tid < rows ? tid : rows - 1;
    toks[tid] = routed ? perm[mbase + r] : (mbase + r);
  }
  __syncthreads();

  const int wid = tid >> 6, lane = tid & 63;
  const int srow = lane >> 3;
  const int kbg  = (lane & 7) ^ (srow & 7);
  const bf16 *aG0, *aG1, *bG0, *bG1;
  int aL0o, aL1o, bL0o, bL1o;
  {
    const int r0 = wid * 16;
    aG0 = x_bf + (size_t)toks[r0 + 0 + srow] * 1024 + kbg * 8;
    aG1 = x_bf + (size_t)toks[r0 + 8 + srow] * 1024 + kbg * 8;
    aL0o = (r0 + 0) * 64; aL1o = (r0 + 8) * 64;
    int b0 = nt * 256 + r0 + 0 + srow; if (b0 > 2045) b0 = 2045;
    int b1 = nt * 256 + r0 + 8 + srow; if (b1 > 2045) b1 = 2045;
    bG0 = bmat + (size_t)b0 * 1024 + kbg * 8;
    bG1 = bmat + (size_t)b1 * 1024 + kbg * 8;
    bL0o = (r0 + 0) * 64; bL1o = (r0 + 8) * 64;
  }

  const int lrow = lane & 15, quad = lane >> 4, sw = lane & 7;
  const int wrow = (wid >> 2) * 64, wcol = (wid & 3) * 64;
  int aoff[4], boff[4], koff[2];
#pragma unroll
  for (int mi = 0; mi < 4; ++mi) aoff[mi] = (wrow + mi * 16 + lrow) * 64;
#pragma unroll
  for (int ni = 0; ni < 4; ++ni) boff[ni] = (wcol + ni * 16 + lrow) * 64;
#pragma unroll
  for (int kk = 0; kk < 2; ++kk) koff[kk] = ((kk * 4 + quad) ^ sw) * 8;

  const floatx4 fz = {0.f, 0.f, 0.f, 0.f};
  floatx4 acc[4][4];
#pragma unroll
  for (int mi = 0; mi < 4; ++mi)
#pragma unroll
    for (int ni = 0; ni < 4; ++ni) acc[mi][ni] = fz;

#define STAGE1(KE, BUF) { \
    load_lds16(aG0 + (KE), Asb[BUF] + aL0o); load_lds16(aG1 + (KE), Asb[BUF] + aL1o); \
    load_lds16(bG0 + (KE), Bsb[BUF] + bL0o); load_lds16(bG1 + (KE), Bsb[BUF] + bL1o); }

#define COMP1(BUF) { \
_Pragma("unroll") \
    for (int kk = 0; kk < 2; ++kk) { \
      bf16x8 av[4], bv[4]; \
_Pragma("unroll") \
      for (int mi = 0; mi < 4; ++mi) av[mi] = *(const bf16x8*)(Asb[BUF] + aoff[mi] + koff[kk]); \
_Pragma("unroll") \
      for (int ni = 0; ni < 4; ++ni) bv[ni] = *(const bf16x8*)(Bsb[BUF] + boff[ni] + koff[kk]); \
_Pragma("unroll") \
      for (int mi = 0; mi < 4; ++mi) \
_Pragma("unroll") \
        for (int ni = 0; ni < 4; ++ni) \
          acc[mi][ni] = MFMA16(av[mi], bv[ni], acc[mi][ni]); \
    } }

  STAGE1(0, 0)
  STAGE1(64, 1)
#pragma unroll 1
  for (int t = 0; t < 7; ++t) {
    const int ke = t * 128;
    WBAR(4); COMP1(0) BARO; STAGE1(ke + 128, 0)
    WBAR(4); COMP1(1) BARO; STAGE1(ke + 192, 1)
  }
  WBAR(4); COMP1(0)
  WBAR(0); COMP1(1)
#undef STAGE1
#undef COMP1

  // epilogue: interleaved cols -> (s1,s3) via lane^1 shuffle, gate, store h(bf16), sumsq
#pragma unroll
  for (int mi = 0; mi < 4; ++mi) {
#pragma unroll
    for (int r = 0; r < 4; ++r) {
      const int row = wrow + mi * 16 + quad * 4 + r;
      const bool rowok = row < rows;
      float ssum = 0.f;
#pragma unroll
      for (int ni = 0; ni < 4; ++ni) {
        const float c = acc[mi][ni][r];
        const float partner = __shfl_xor(c, 1);
        const float s1 = (lane & 1) ? partner : c;
        const float s3 = (lane & 1) ? c : partner;
        const float sp = (s1 / (1.f + __expf(-s1))) * s3;
        const int P = (nt * 256 + wcol + ni * 16 + lrow) >> 1;
        const bool ok = rowok && ((lane & 1) == 0) && (P < 1023);
        if (ok) hbuf[(size_t)(mbase + row) * 1024 + 1 + P] = (bf16)sp;
        ssum += ok ? sp * sp : 0.f;
      }
      ssum += __shfl_xor(ssum, 1);
      ssum += __shfl_xor(ssum, 2);
      ssum += __shfl_xor(ssum, 4);
      ssum += __shfl_xor(ssum, 8);
      if (lrow == 0 && rowok) atomicAdd(ssbuf + mbase + row, ssum);
    }
  }
}

// ---------------- mlp2: BM=256 x BN=256, SPLIT-K x2, dual buffers + fused COMBINE ----------------
// After the tile stores, each block claims its tokens via tokcnt (16 contributions per
// token: 8 shared-slot + 8 routed-slot blocks). The 16th incrementer (old%16==15 — mod
// trick, no zeroing) acquire-fences and performs the LResNet combine for that token row.
__global__ __launch_bounds__(1024) void mlp2_kernel(
    const bf16* __restrict__ h_r, const bf16* __restrict__ h_s,
    const bf16* __restrict__ w2b, const bf16* __restrict__ ws2b,
    const int4* __restrict__ wl, const int* __restrict__ wl_n,
    const int* __restrict__ perm,
    float* __restrict__ o_r0, float* __restrict__ o_r1,
    float* __restrict__ o_s0, float* __restrict__ o_s1,
    const float* __restrict__ ss_r, const float* __restrict__ ss_z,
    const float* __restrict__ w2c0_r, const float* __restrict__ w2c0_s,
    const int* __restrict__ eidx, const int* __restrict__ pos_of,
    const float* __restrict__ wgt,
    unsigned* __restrict__ tokcnt, float* __restrict__ out)
{
  const int bid = blockIdx.x;
  const int slot = bid % SMAX;
  const int rest = bid / SMAX;        // 0..7
  const int nt = rest & 3, kh = rest >> 2;
  if (slot >= *wl_n) return;
  const int4 wle = wl[slot];
  const int mbase = wle.x, rows = wle.y, eid = wle.z;
  const int tid = threadIdx.x;
  const bool routed = (eid < NE);
  const bf16* abuf = routed ? h_r : h_s;
  const bf16* bmat = routed ? w2b + (size_t)eid * 1023 * 1024 : ws2b;
  float* obuf = routed ? (kh ? o_r1 : o_r0) : (kh ? o_s1 : o_s0);
  const int n0 = nt * 256;
  const int kbase = kh * 512;

  extern __shared__ __align__(16) bf16 smem[];
  bf16* const Asb[2] = {smem, smem + 16384};            // 256x64 each
  bf16* const Bsb[2] = {smem + 32768, smem + 49152};    // 256x64 each

  const int wid = tid >> 6, lane = tid & 63;
  const int srow = lane >> 3;
  const int kbg  = (lane & 7) ^ (srow & 7);
  const bf16 *aG0, *aG1, *bG0, *bG1;
  int aL0o, aL1o, bL0o, bL1o;
  {
    const int r0 = wid * 16;
    int ra0 = r0 + 0 + srow; if (ra0 >= rows) ra0 = rows - 1;
    int ra1 = r0 + 8 + srow; if (ra1 >= rows) ra1 = rows - 1;
    aG0 = abuf + (size_t)(mbase + ra0) * 1024 + kbase + kbg * 8;
    aG1 = abuf + (size_t)(mbase + ra1) * 1024 + kbase + kbg * 8;
    aL0o = (r0 + 0) * 64; aL1o = (r0 + 8) * 64;
    int b0 = n0 + r0 + 0 + srow; if (b0 > 1022) b0 = 1022;
    int b1 = n0 + r0 + 8 + srow; if (b1 > 1022) b1 = 1022;
    bG0 = bmat + (size_t)b0 * 1024 + kbase + kbg * 8;
    bG1 = bmat + (size_t)b1 * 1024 + kbase + kbg * 8;
    bL0o = (r0 + 0) * 64; bL1o = (r0 + 8) * 64;
  }

  const int lrow = lane & 15, quad = lane >> 4, sw = lane & 7;
  const int wrow = (wid >> 2) * 64, wcol = (wid & 3) * 64;
  int aoff[4], boff[4], koff[2];
#pragma unroll
  for (int mi = 0; mi < 4; ++mi) aoff[mi] = (wrow + mi * 16 + lrow) * 64;
#pragma unroll
  for (int ni = 0; ni < 4; ++ni) boff[ni] = (wcol + ni * 16 + lrow) * 64;
#pragma unroll
  for (int kk = 0; kk < 2; ++kk) koff[kk] = ((kk * 4 + quad) ^ sw) * 8;

  const floatx4 fz = {0.f, 0.f, 0.f, 0.f};
  floatx4 acc[4][4];
#pragma unroll
  for (int mi = 0; mi < 4; ++mi)
#pragma unroll
    for (int ni = 0; ni < 4; ++ni) acc[mi][ni] = fz;

#define STAGE2(KE, BUF) { \
    load_lds16(aG0 + (KE), Asb[BUF] + aL0o); load_lds16(aG1 + (KE), Asb[BUF] + aL1o); \
    load_lds16(bG0 + (KE), Bsb[BUF] + bL0o); load_lds16(bG1 + (KE), Bsb[BUF] + bL1o); }

#define COMP2(BUF) { \
_Pragma("unroll") \
    for (int kk = 0; kk < 2; ++kk) { \
      bf16x8 av[4], bv[4]; \
_Pragma("unroll") \
      for (int mi = 0; mi < 4; ++mi) av[mi] = *(const bf16x8*)(Asb[BUF] + aoff[mi] + koff[kk]); \
_Pragma("unroll") \
      for (int ni = 0; ni < 4; ++ni) bv[ni] = *(const bf16x8*)(Bsb[BUF] + boff[ni] + koff[kk]); \
_Pragma("unroll") \
      for (int mi = 0; mi < 4; ++mi) \
_Pragma("unroll") \
        for (int ni = 0; ni < 4; ++ni) \
          acc[mi][ni] = MFMA16(av[mi], bv[ni], acc[mi][ni]); \
    } }

  // 8 K-steps (this block's half of K)
  STAGE2(0, 0)
  STAGE2(64, 1)
#pragma unroll 1
  for (int t = 0; t < 3; ++t) {
    const int ke = t * 128;
    WBAR(4); COMP2(0) BARO; STAGE2(ke + 128, 0)
    WBAR(4); COMP2(1) BARO; STAGE2(ke + 192, 1)
  }
  WBAR(4); COMP2(0)
  WBAR(0); COMP2(1)
#undef STAGE2
#undef COMP2

  // epilogue: plain fp32 stores into this kh's buffer
#pragma unroll
  for (int mi = 0; mi < 4; ++mi) {
#pragma unroll
    for (int r = 0; r < 4; ++r) {
      const int row = wrow + mi * 16 + quad * 4 + r;
      if (row < rows) {
        float* orow = obuf + (size_t)(mbase + row) * 1024;
#pragma unroll
        for (int ni = 0; ni < 4; ++ni) {
          const int n = n0 + wcol + ni * 16 + lrow;
          if (n < 1023) orow[n] = acc[mi][ni][r];
        }
      }
    }
  }

  // ---- claim tokens; 16th contributor combines the row ----
  __shared__ int wtok[256];
  __shared__ int wcnt;
  __shared__ float rs[3][4];
  if (tid == 0) wcnt = 0;
  __syncthreads();                       // all waves' stores drained (vmcnt at barrier)
  __threadfence();                       // release: this block's tile visible device-wide
  if (tid < rows) {
    const int t = routed ? perm[mbase + tid] : (mbase + tid);
    const unsigned old = atomicAdd(&tokcnt[t], 1u);
    if ((old & 15u) == 15u) {
      const int i = atomicAdd(&wcnt, 1);
      wtok[i] = t;
    }
  }
  __syncthreads();
  const int nw = wcnt;
  if (nw == 0) return;
  __threadfence();                       // acquire: other blocks' tiles visible

  for (int i = 0; i < nw; ++i) {
    const int t = wtok[i];
    float c0 = 0.f, c1 = 0.f, c2 = 0.f, c3 = 0.f;
    float sc = 0.f, sz = 0.f, sr = 0.f;
    if (tid < 256) {
      const int p = pos_of[t];
      const int e = eidx[t];
      const float w = wgt[t];
      const float tz = sqrtf(ss_z[t] + 1.f);
      const float tr = sqrtf(ss_r[p] + 1.f);
      const float4 oz0 = ((const float4*)(o_s0 + (size_t)t * 1024))[tid];
      const float4 oz1 = ((const float4*)(o_s1 + (size_t)t * 1024))[tid];
      const float4 oe0 = ((const float4*)(o_r0 + (size_t)p * 1024))[tid];
      const float4 oe1 = ((const float4*)(o_r1 + (size_t)p * 1024))[tid];
      const float4 c0s = ((const float4*)(w2c0_s))[tid];
      const float4 c0r = ((const float4*)(w2c0_r + (size_t)e * 1024))[tid];
      const bool last = (tid == 255);    // n=1023 is padding
      const float ozf0 = oz0.x + oz1.x + tz * c0s.x;
      const float ozf1 = oz0.y + oz1.y + tz * c0s.y;
      const float ozf2 = oz0.z + oz1.z + tz * c0s.z;
      const float ozf3 = last ? 0.f : (oz0.w + oz1.w + tz * c0s.w);
      const float oef0 = oe0.x + oe1.x + tr * c0r.x;
      const float oef1 = oe0.y + oe1.y + tr * c0r.y;
      const float oef2 = oe0.z + oe1.z + tr * c0r.z;
      const float oef3 = last ? 0.f : (oe0.w + oe1.w + tr * c0r.w);
      const float tw = 2.f * w;
      c0 = ozf0 + tw * oef0;
      c1 = ozf1 + tw * oef1;
      c2 = ozf2 + tw * oef2;
      c3 = ozf3 + tw * oef3;
      sc = c0 * c0 + c1 * c1 + c2 * c2 + c3 * c3;
      sz = ozf0 * ozf0 + ozf1 * ozf1 + ozf2 * ozf2 + ozf3 * ozf3;
      sr = oef0 * oef0 + oef1 * oef1 + oef2 * oef2 + oef3 * oef3;
#pragma unroll
      for (int off = 32; off > 0; off >>= 1) {
        sc += __shfl_down(sc, off);
        sz += __shfl_down(sz, off);
        sr += __shfl_down(sr, off);
      }
      if (lane == 0) { rs[0][wid] = sc; rs[1][wid] = sz; rs[2][wid] = sr; }
    }
    __syncthreads();
    if (tid < 256) {
      const float space2 = rs[0][0] + rs[0][1] + rs[0][2] + rs[0][3];
      const float ss_oz  = rs[1][0] + rs[1][1] + rs[1][2] + rs[1][3];
      const float ss_or  = rs[2][0] + rs[2][1] + rs[2][2] + rs[2][3];
      const float w = wgt[t];
      const float comb0 = sqrtf(ss_oz + 1.f) + 2.f + 2.f * w * sqrtf(ss_or + 1.f);
      const float li = space2 - comb0 * comb0;
      const float inv = 1.f / sqrtf(fmaxf(fabsf(li), 1e-8f));
      float* orow = out + (size_t)t * 1024;
      const int j = 1 + tid * 4;
      orow[j]     = c0 * inv;
      orow[j + 1] = c1 * inv;
      orow[j + 2] = c2 * inv;
      if (tid != 255) orow[j + 3] = c3 * inv;
      if (tid == 0) orow[0] = comb0 * inv;
    }
    __syncthreads();                     // rs reuse next iteration
  }
}

extern "C" void kernel_launch(void* const* d_in, const int* in_sizes, int n_in,
                              void* d_out, int out_size, void* d_ws, size_t ws_size,
                              hipStream_t stream) {
  const float* x      = (const float*)d_in[0];
  const float* gate_w = (const float*)d_in[1];
  const float* gate_b = (const float*)d_in[2];
  const float* W1     = (const float*)d_in[3];
  const float* W3     = (const float*)d_in[4];
  const float* W2     = (const float*)d_in[5];
  const float* Ws1    = (const float*)d_in[6];
  const float* Ws3    = (const float*)d_in[7];
  const float* Ws2    = (const float*)d_in[8];
  float* out = (float*)d_out;

  char* ws = (char*)d_ws;
  size_t off = 0;
  auto alloc = [&](size_t bytes) {
    void* p = ws + off;
    off += (bytes + 255) & ~(size_t)255;
    return p;
  };
  bf16*  x_bf = (bf16*) alloc((size_t)TOK * 1024 * 2);
  bf16*  h_r  = (bf16*) alloc((size_t)TOK * 1024 * 2);
  bf16*  h_s  = (bf16*) alloc((size_t)TOK * 1024 * 2);
  float* o_r0 = (float*)alloc((size_t)TOK * 1024 * 4);
  float* o_s0 = (float*)alloc((size_t)TOK * 1024 * 4);
  float* ss   = (float*)alloc((size_t)2 * TOK * 4);
  int*   eidx = (int*)  alloc((size_t)TOK * 4);
  float* ewgt = (float*)alloc((size_t)TOK * 4);
  int*   perm = (int*)  alloc((size_t)TOK * 4);
  int*   posf = (int*)  alloc((size_t)TOK * 4);
  int4*  wl1  = (int4*) alloc((size_t)SMAX * 16);
  int*   wn   = (int*)  alloc(32);
  unsigned* done   = (unsigned*)alloc(32);
  unsigned* tokcnt = (unsigned*)alloc((size_t)TOK * 4);
  float* w2c0_r = (float*)alloc((size_t)NE * 1024 * 4);   // padded [E][1024]
  float* w2c0_s = (float*)alloc((size_t)1024 * 4);
  bf16*  w13  = (bf16*) alloc((size_t)8 * 2046 * 1024 * 2);
  bf16*  ws13 = (bf16*) alloc((size_t)2046 * 1024 * 2);
  bf16*  w2b  = (bf16*) alloc((size_t)8 * 1023 * 1024 * 2);
  bf16*  ws2b = (bf16*) alloc((size_t)1023 * 1024 * 2);

  // split-K second-half buffers ALIAS the w13 region (w13 is dead after mlp1).
  float* o_r1 = (float*)w13;
  float* o_s1 = (float*)w13 + (size_t)TOK * 1024;

  float* ss_r  = ss;
  float* ss_z  = ss + TOK;

  // both MLP kernels use 128KB dynamic LDS (dbuf 256x64 A + 256x64 B)
  const int MLP_LDS = 2 * (256 * 64 + 256 * 64) * 2;  // 131072 B
  (void)hipFuncSetAttribute((const void*)mlp1_kernel,
                            hipFuncAttributeMaxDynamicSharedMemorySize, MLP_LDS);
  (void)hipFuncSetAttribute((const void*)mlp2_kernel,
                            hipFuncAttributeMaxDynamicSharedMemorySize, MLP_LDS);

  prep_kernel<<<GATEB + NCVT2, 256, 0, stream>>>(
      x, gate_w, gate_b, W1, W3, W2, Ws1, Ws3, Ws2,
      x_bf, eidx, ewgt, ss, w13, ws13, w2b, ws2b, w2c0_r, w2c0_s, h_r, h_s,
      done, perm, posf, wl1, wn);
  mlp1_kernel<<<8 * SMAX, 1024, MLP_LDS, stream>>>(x_bf, w13, ws13, perm, wl1, wn,
                                                   h_r, h_s, ss_r, ss_z);
  mlp2_kernel<<<8 * SMAX, 1024, MLP_LDS, stream>>>(h_r, h_s, w2b, ws2b, wl1, wn, perm,
                                                   o_r0, o_r1, o_s0, o_s1,
                                                   ss_r, ss_z, w2c0_r, w2c0_s,
                                                   eidx, posf, ewgt, tokcnt, out);
}

// Round 10
// 250.898 us; speedup vs baseline: 2.8718x; 2.8718x over previous
//
#include <hip/hip_runtime.h>

typedef __bf16 bf16;
typedef __attribute__((ext_vector_type(8))) __bf16 bf16x8;
typedef __attribute__((ext_vector_type(4))) float floatx4;

#define TOK 2048
#define DD  1024
#define NE  8
#define SMAX 24    // worklist slots (BM=256): <=15 routed + 8 shared, padded to %8==0
#define GRID2 (8 * SMAX)   // mlp2 grid: 192 blocks = 1/CU -> all co-resident

#define MFMA16(A,B,C) __builtin_amdgcn_mfma_f32_16x16x32_bf16(A,B,C,0,0,0)

__device__ __forceinline__ void load_lds16(const bf16* g, bf16* l) {
  __builtin_amdgcn_global_load_lds(
      (const __attribute__((address_space(1))) void*)g,
      (__attribute__((address_space(3))) void*)l, 16, 0, 0);
}

// fine-grained barrier: wait only the OLDEST outstanding loads, keep N in flight
#define WBAR(N) asm volatile("s_waitcnt vmcnt(" #N ")\n\ts_barrier" ::: "memory")
#define BARO    asm volatile("s_barrier" ::: "memory")

// ---------------- prep: gate + x->bf16 + weight fp32->bf16 convert + w2col0 extract ----------------
// (r7-verbatim: 50us proven.)
#define NCVT (8*2046 + 2046 + 8*1023 + 1023)
#define GATEB TOK
__global__ __launch_bounds__(256) void prep_kernel(
    const float* __restrict__ x, const float* __restrict__ gate_w,
    const float* __restrict__ gate_b,
    const float* __restrict__ W1, const float* __restrict__ W3,
    const float* __restrict__ W2, const float* __restrict__ Ws1,
    const float* __restrict__ Ws3, const float* __restrict__ Ws2,
    bf16* __restrict__ x_bf, int* __restrict__ eidx, float* __restrict__ ewgt,
    float* __restrict__ ss,
    bf16* __restrict__ w13, bf16* __restrict__ ws13,
    bf16* __restrict__ w2b, bf16* __restrict__ ws2b,
    float* __restrict__ w2c0_r, float* __restrict__ w2c0_s,
    bf16* __restrict__ h_r, bf16* __restrict__ h_s)
{
  const int bid = blockIdx.x, tid = threadIdx.x;

  if (bid >= GATEB) {
    // ---- weight convert (W1/W3 row-interleaved), 4 floats/thread ----
    const int r = bid - GATEB;
    const float* src; bf16* dst;
    float* c0dst = nullptr;
    if (r < 8 * 2046) {
      const int e = r / 2046, q = r % 2046;
      src = ((q & 1) ? W3 : W1) + ((size_t)e * 1023 + (q >> 1)) * 1024;
      dst = w13 + (size_t)r * 1024;
    } else if (r < 8 * 2046 + 2046) {
      const int q = r - 8 * 2046;
      src = ((q & 1) ? Ws3 : Ws1) + (size_t)(q >> 1) * 1024;
      dst = ws13 + (size_t)q * 1024;
    } else if (r < 8 * 2046 + 2046 + 8 * 1023) {
      const int q = r - (8 * 2046 + 2046);
      src = W2 + (size_t)q * 1024;
      dst = w2b + (size_t)q * 1024;
      c0dst = w2c0_r + (size_t)(q / 1023) * 1024 + (q % 1023);  // padded [E][1024]
    } else {
      const int q = r - (8 * 2046 + 2046 + 8 * 1023);
      src = Ws2 + (size_t)q * 1024;
      dst = ws2b + (size_t)q * 1024;
      c0dst = w2c0_s + q;
    }
    const float4 f = ((const float4*)src)[tid];
    if (tid == 0 && c0dst) *c0dst = f.x;   // W2[:,0] (time-lift column)
    union { bf16 h[4]; uint2 u; } p;
    p.h[0] = (bf16)f.x; p.h[1] = (bf16)f.y; p.h[2] = (bf16)f.z; p.h[3] = (bf16)f.w;
    ((uint2*)dst)[tid] = p.u;
    return;
  }

  // ---- gate + x->bf16 + ss zero (ss_r, ss_z) + h[:,0]=0 ----
  const int t = bid;
  if (tid < 2) ss[tid * TOK + t] = 0.f;
  if (tid == 2) h_r[(size_t)t * 1024] = (bf16)0.f;
  if (tid == 3) h_s[(size_t)t * 1024] = (bf16)0.f;
  const float4 v = ((const float4*)(x + (size_t)t * DD))[tid];
  union { bf16 h[4]; uint2 u; } pk;
  pk.h[0] = (bf16)v.x; pk.h[1] = (bf16)v.y; pk.h[2] = (bf16)v.z; pk.h[3] = (bf16)v.w;
  ((uint2*)(x_bf + (size_t)t * DD))[tid] = pk.u;

  float acc[NE];
#pragma unroll
  for (int e = 0; e < NE; ++e) acc[e] = 0.f;
  const float vv[4] = {v.x, v.y, v.z, v.w};
#pragma unroll
  for (int i = 0; i < 4; ++i) {
    const int d = tid * 4 + i;
    if (d >= 1) {
#pragma unroll
      for (int e = 0; e < NE; ++e) acc[e] += vv[i] * gate_w[e * (DD - 1) + d - 1];
    }
  }
#pragma unroll
  for (int off = 32; off > 0; off >>= 1) {
#pragma unroll
    for (int e = 0; e < NE; ++e) acc[e] += __shfl_down(acc[e], off);
  }
  __shared__ float red[4][NE];
  const int wid = tid >> 6, lane = tid & 63;
  if (lane == 0) {
#pragma unroll
    for (int e = 0; e < NE; ++e) red[wid][e] = acc[e];
  }
  __syncthreads();
  if (tid == 0) {
    float lg[NE];
#pragma unroll
    for (int e = 0; e < NE; ++e) lg[e] = red[0][e] + red[1][e] + red[2][e] + red[3][e];
    float m = lg[0];
    for (int e = 1; e < NE; ++e) m = fmaxf(m, lg[e]);
    float ex[NE], s = 0.f;
    for (int e = 0; e < NE; ++e) { ex[e] = expf(lg[e] - m); s += ex[e]; }
    const float inv = 1.f / s;
    int best = 0; float bb = ex[0] * inv + gate_b[0];
    for (int e = 1; e < NE; ++e) {
      const float b = ex[e] * inv + gate_b[e];
      if (b > bb) { bb = b; best = e; }
    }
    eidx[t] = best;
    ewgt[t] = ex[best] * inv;
  }
}

// ---------------- routing: count + prefix + scatter + worklist + done2 RESET ----------------
// Single block, stream-ordered before mlp2: zeroing done2 here restores the aligned-window
// invariant the r9 grid barrier needs (workspace is POISONED by the harness each run —
// garbage start deadlocked r9).
__global__ __launch_bounds__(256) void route_kernel(
    const int* __restrict__ eidx, int* __restrict__ perm,
    int* __restrict__ pos_of, int4* __restrict__ wl, int* __restrict__ n1,
    unsigned* __restrict__ done2)
{
  __shared__ int cnt[NE], off[NE], bas[NE + 1];
  const int tid = threadIdx.x;
  if (tid == 0) *done2 = 0u;
  if (tid < NE) cnt[tid] = 0;
  __syncthreads();
  for (int t = tid; t < TOK; t += 256) atomicAdd(&cnt[eidx[t]], 1);
  __syncthreads();
  if (tid == 0) {
    int run = 0;
    for (int e = 0; e < NE; ++e) { bas[e] = run; off[e] = run; run += cnt[e]; }
    bas[NE] = run;
    int n = 0;
    for (int e = 0; e < NE; ++e)
      for (int r0 = 0; r0 < cnt[e]; r0 += 256) {
        int rows = cnt[e] - r0; if (rows > 256) rows = 256;
        wl[n++] = make_int4(bas[e] + r0, rows, e, 0);
      }
    for (int r0 = 0; r0 < TOK; r0 += 256) wl[n++] = make_int4(r0, 256, NE, 0);
    *n1 = n;
  }
  __syncthreads();
  for (int t = tid; t < TOK; t += 256) {
    const int e = eidx[t];
    const int p = atomicAdd(&off[e], 1);
    perm[p] = t;
    pos_of[t] = p;
  }
}

// ---------------- mlp1: BM=256 x BN=256 x BK=64, 16 waves, dbuf + vmcnt(4) ----------------
// UNCHANGED control (measured 44us, 0 conflicts, best per-CU staging rate).
__global__ __launch_bounds__(1024) void mlp1_kernel(
    const bf16* __restrict__ x_bf, const bf16* __restrict__ w13,
    const bf16* __restrict__ ws13,
    const int* __restrict__ perm, const int4* __restrict__ wl,
    const int* __restrict__ wl_n,
    bf16* __restrict__ h_r, bf16* __restrict__ h_s,
    float* __restrict__ ss_r, float* __restrict__ ss_z)
{
  const int bid = blockIdx.x;
  const int slot = bid % SMAX, nt = bid / SMAX;   // nt in 0..7
  if (slot >= *wl_n) return;
  const int4 wle = wl[slot];
  const int mbase = wle.x, rows = wle.y, eid = wle.z;
  const int tid = threadIdx.x;
  const bool routed = (eid < NE);
  const bf16* bmat = routed ? w13 + (size_t)eid * 2046 * 1024 : ws13;
  bf16* hbuf  = routed ? h_r : h_s;
  float* ssbuf = routed ? ss_r : ss_z;

  extern __shared__ __align__(16) bf16 smem[];
  bf16* const Asb[2] = {smem, smem + 16384};            // 256x64 each
  bf16* const Bsb[2] = {smem + 32768, smem + 49152};    // 256x64 each
  __shared__ int toks[256];
  if (tid < 256) {
    int r = tid < rows ? tid : rows - 1;
    toks[tid] = routed ? perm[mbase + r] : (mbase + r);
  }
  __syncthreads();

  const int wid = tid >> 6, lane = tid & 63;
  const int srow = lane >> 3;
  const int kbg  = (lane & 7) ^ (srow & 7);
  const bf16 *aG0, *aG1, *bG0, *bG1;
  int aL0o, aL1o, bL0o, bL1o;
  {
    const int r0 = wid * 16;
    aG0 = x_bf + (size_t)toks[r0 + 0 + srow] * 1024 + kbg * 8;
    aG1 = x_bf + (size_t)toks[r0 + 8 + srow] * 1024 + kbg * 8;
    aL0o = (r0 + 0) * 64; aL1o = (r0 + 8) * 64;
    int b0 = nt * 256 + r0 + 0 + srow; if (b0 > 2045) b0 = 2045;
    int b1 = nt * 256 + r0 + 8 + srow; if (b1 > 2045) b1 = 2045;
    bG0 = bmat + (size_t)b0 * 1024 + kbg * 8;
    bG1 = bmat + (size_t)b1 * 1024 + kbg * 8;
    bL0o = (r0 + 0) * 64; bL1o = (r0 + 8) * 64;
  }

  const int lrow = lane & 15, quad = lane >> 4, sw = lane & 7;
  const int wrow = (wid >> 2) * 64, wcol = (wid & 3) * 64;
  int aoff[4], boff[4], koff[2];
#pragma unroll
  for (int mi = 0; mi < 4; ++mi) aoff[mi] = (wrow + mi * 16 + lrow) * 64;
#pragma unroll
  for (int ni = 0; ni < 4; ++ni) boff[ni] = (wcol + ni * 16 + lrow) * 64;
#pragma unroll
  for (int kk = 0; kk < 2; ++kk) koff[kk] = ((kk * 4 + quad) ^ sw) * 8;

  const floatx4 fz = {0.f, 0.f, 0.f, 0.f};
  floatx4 acc[4][4];
#pragma unroll
  for (int mi = 0; mi < 4; ++mi)
#pragma unroll
    for (int ni = 0; ni < 4; ++ni) acc[mi][ni] = fz;

#define STAGE1(KE, BUF) { \
    load_lds16(aG0 + (KE), Asb[BUF] + aL0o); load_lds16(aG1 + (KE), Asb[BUF] + aL1o); \
    load_lds16(bG0 + (KE), Bsb[BUF] + bL0o); load_lds16(bG1 + (KE), Bsb[BUF] + bL1o); }

#define COMP1(BUF) { \
_Pragma("unroll") \
    for (int kk = 0; kk < 2; ++kk) { \
      bf16x8 av[4], bv[4]; \
_Pragma("unroll") \
      for (int mi = 0; mi < 4; ++mi) av[mi] = *(const bf16x8*)(Asb[BUF] + aoff[mi] + koff[kk]); \
_Pragma("unroll") \
      for (int ni = 0; ni < 4; ++ni) bv[ni] = *(const bf16x8*)(Bsb[BUF] + boff[ni] + koff[kk]); \
_Pragma("unroll") \
      for (int mi = 0; mi < 4; ++mi) \
_Pragma("unroll") \
        for (int ni = 0; ni < 4; ++ni) \
          acc[mi][ni] = MFMA16(av[mi], bv[ni], acc[mi][ni]); \
    } }

  STAGE1(0, 0)
  STAGE1(64, 1)
#pragma unroll 1
  for (int t = 0; t < 7; ++t) {
    const int ke = t * 128;
    WBAR(4); COMP1(0) BARO; STAGE1(ke + 128, 0)
    WBAR(4); COMP1(1) BARO; STAGE1(ke + 192, 1)
  }
  WBAR(4); COMP1(0)
  WBAR(0); COMP1(1)
#undef STAGE1
#undef COMP1

  // epilogue: interleaved cols -> (s1,s3) via lane^1 shuffle, gate, store h(bf16), sumsq
#pragma unroll
  for (int mi = 0; mi < 4; ++mi) {
#pragma unroll
    for (int r = 0; r < 4; ++r) {
      const int row = wrow + mi * 16 + quad * 4 + r;
      const bool rowok = row < rows;
      float ssum = 0.f;
#pragma unroll
      for (int ni = 0; ni < 4; ++ni) {
        const float c = acc[mi][ni][r];
        const float partner = __shfl_xor(c, 1);
        const float s1 = (lane & 1) ? partner : c;
        const float s3 = (lane & 1) ? c : partner;
        const float sp = (s1 / (1.f + __expf(-s1))) * s3;
        const int P = (nt * 256 + wcol + ni * 16 + lrow) >> 1;
        const bool ok = rowok && ((lane & 1) == 0) && (P < 1023);
        if (ok) hbuf[(size_t)(mbase + row) * 1024 + 1 + P] = (bf16)sp;
        ssum += ok ? sp * sp : 0.f;
      }
      ssum += __shfl_xor(ssum, 1);
      ssum += __shfl_xor(ssum, 2);
      ssum += __shfl_xor(ssum, 4);
      ssum += __shfl_xor(ssum, 8);
      if (lrow == 0 && rowok) atomicAdd(ssbuf + mbase + row, ssum);
    }
  }
}

// ---------------- mlp2: split-K x2 GEMM + grid barrier + BALANCED fused combine ----------------
// Grid = 192 blocks (1 block/CU by LDS, < 256 CUs -> all co-resident). Barrier counter is
// zeroed by route_kernel each launch (poisoned-workspace deadlock fix); spin-load uses a
// device-scope atomic RMW (coherent across XCDs) with s_sleep backoff.
__global__ __launch_bounds__(1024) void mlp2_kernel(
    const bf16* __restrict__ h_r, const bf16* __restrict__ h_s,
    const bf16* __restrict__ w2b, const bf16* __restrict__ ws2b,
    const int4* __restrict__ wl, const int* __restrict__ wl_n,
    float* __restrict__ o_r0, float* __restrict__ o_r1,
    float* __restrict__ o_s0, float* __restrict__ o_s1,
    const float* __restrict__ ss_r, const float* __restrict__ ss_z,
    const float* __restrict__ w2c0_r, const float* __restrict__ w2c0_s,
    const int* __restrict__ eidx, const int* __restrict__ pos_of,
    const float* __restrict__ wgt,
    unsigned* __restrict__ done2, float* __restrict__ out)
{
  const int bid = blockIdx.x;
  const int slot = bid % SMAX;
  const int rest = bid / SMAX;        // 0..7
  const int nt = rest & 3, kh = rest >> 2;
  const int tid = threadIdx.x;
  const int wid = tid >> 6, lane = tid & 63;
  extern __shared__ __align__(16) bf16 smem[];
  const bool active = (slot < *wl_n);

  if (active) {
    const int4 wle = wl[slot];
    const int mbase = wle.x, rows = wle.y, eid = wle.z;
    const bool routed = (eid < NE);
    const bf16* abuf = routed ? h_r : h_s;
    const bf16* bmat = routed ? w2b + (size_t)eid * 1023 * 1024 : ws2b;
    float* obuf = routed ? (kh ? o_r1 : o_r0) : (kh ? o_s1 : o_s0);
    const int n0 = nt * 256;
    const int kbase = kh * 512;

    bf16* const Asb[2] = {smem, smem + 16384};            // 256x64 each
    bf16* const Bsb[2] = {smem + 32768, smem + 49152};    // 256x64 each

    const int srow = lane >> 3;
    const int kbg  = (lane & 7) ^ (srow & 7);
    const bf16 *aG0, *aG1, *bG0, *bG1;
    int aL0o, aL1o, bL0o, bL1o;
    {
      const int r0 = wid * 16;
      int ra0 = r0 + 0 + srow; if (ra0 >= rows) ra0 = rows - 1;
      int ra1 = r0 + 8 + srow; if (ra1 >= rows) ra1 = rows - 1;
      aG0 = abuf + (size_t)(mbase + ra0) * 1024 + kbase + kbg * 8;
      aG1 = abuf + (size_t)(mbase + ra1) * 1024 + kbase + kbg * 8;
      aL0o = (r0 + 0) * 64; aL1o = (r0 + 8) * 64;
      int b0 = n0 + r0 + 0 + srow; if (b0 > 1022) b0 = 1022;
      int b1 = n0 + r0 + 8 + srow; if (b1 > 1022) b1 = 1022;
      bG0 = bmat + (size_t)b0 * 1024 + kbase + kbg * 8;
      bG1 = bmat + (size_t)b1 * 1024 + kbase + kbg * 8;
      bL0o = (r0 + 0) * 64; bL1o = (r0 + 8) * 64;
    }

    const int lrow = lane & 15, quad = lane >> 4, sw = lane & 7;
    const int wrow = (wid >> 2) * 64, wcol = (wid & 3) * 64;
    int aoff[4], boff[4], koff[2];
#pragma unroll
    for (int mi = 0; mi < 4; ++mi) aoff[mi] = (wrow + mi * 16 + lrow) * 64;
#pragma unroll
    for (int ni = 0; ni < 4; ++ni) boff[ni] = (wcol + ni * 16 + lrow) * 64;
#pragma unroll
    for (int kk = 0; kk < 2; ++kk) koff[kk] = ((kk * 4 + quad) ^ sw) * 8;

    const floatx4 fz = {0.f, 0.f, 0.f, 0.f};
    floatx4 acc[4][4];
#pragma unroll
    for (int mi = 0; mi < 4; ++mi)
#pragma unroll
      for (int ni = 0; ni < 4; ++ni) acc[mi][ni] = fz;

#define STAGE2(KE, BUF) { \
    load_lds16(aG0 + (KE), Asb[BUF] + aL0o); load_lds16(aG1 + (KE), Asb[BUF] + aL1o); \
    load_lds16(bG0 + (KE), Bsb[BUF] + bL0o); load_lds16(bG1 + (KE), Bsb[BUF] + bL1o); }

#define COMP2(BUF) { \
_Pragma("unroll") \
    for (int kk = 0; kk < 2; ++kk) { \
      bf16x8 av[4], bv[4]; \
_Pragma("unroll") \
      for (int mi = 0; mi < 4; ++mi) av[mi] = *(const bf16x8*)(Asb[BUF] + aoff[mi] + koff[kk]); \
_Pragma("unroll") \
      for (int ni = 0; ni < 4; ++ni) bv[ni] = *(const bf16x8*)(Bsb[BUF] + boff[ni] + koff[kk]); \
_Pragma("unroll") \
      for (int mi = 0; mi < 4; ++mi) \
_Pragma("unroll") \
        for (int ni = 0; ni < 4; ++ni) \
          acc[mi][ni] = MFMA16(av[mi], bv[ni], acc[mi][ni]); \
    } }

    // 8 K-steps (this block's half of K)
    STAGE2(0, 0)
    STAGE2(64, 1)
#pragma unroll 1
    for (int t = 0; t < 3; ++t) {
      const int ke = t * 128;
      WBAR(4); COMP2(0) BARO; STAGE2(ke + 128, 0)
      WBAR(4); COMP2(1) BARO; STAGE2(ke + 192, 1)
    }
    WBAR(4); COMP2(0)
    WBAR(0); COMP2(1)
#undef STAGE2
#undef COMP2

    // epilogue: plain fp32 stores into this kh's buffer
#pragma unroll
    for (int mi = 0; mi < 4; ++mi) {
#pragma unroll
      for (int r = 0; r < 4; ++r) {
        const int row = wrow + mi * 16 + quad * 4 + r;
        if (row < rows) {
          float* orow = obuf + (size_t)(mbase + row) * 1024;
#pragma unroll
          for (int ni = 0; ni < 4; ++ni) {
            const int n = n0 + wcol + ni * 16 + lrow;
            if (n < 1023) orow[n] = acc[mi][ni][r];
          }
        }
      }
    }
  }

  // ---- grid-wide barrier (all GRID2 blocks co-resident; done2 zeroed by route) ----
  __syncthreads();                       // all waves' stores drained (vmcnt at barrier)
  if (tid == 0) {
    __threadfence();                     // release: cache-wide L2 writeback (1 per block)
    const unsigned m = atomicAdd(done2, 1u);
    const unsigned tgt = (m / (unsigned)GRID2 + 1u) * (unsigned)GRID2;
    while (atomicOr(done2, 0u) < tgt)    // device-scope coherent read
      __builtin_amdgcn_s_sleep(32);
    __threadfence();                     // acquire: invalidate stale lines
  }
  __syncthreads();

  // ---- balanced combine: 768 row-engines over 2048 token rows, 3 rounds ----
  __shared__ float rs2[4][3][4];
  const int grp = tid >> 8;              // 0..3 (256-thread row group)
  const int q   = tid & 255;             // float4 index within the row
  const int gw  = (tid >> 6) & 3;        // wave within group
  const int eng = bid * 4 + grp;         // 0..767
#pragma unroll 1
  for (int rnd = 0; rnd < 3; ++rnd) {
    const int t = eng + rnd * 768;
    const bool valid = t < TOK;
    float c0 = 0.f, c1 = 0.f, c2 = 0.f, c3 = 0.f;
    float wv = 0.f;
    if (valid) {
      const int p = pos_of[t];
      const int e = eidx[t];
      wv = wgt[t];
      const float tz = sqrtf(ss_z[t] + 1.f);
      const float tr = sqrtf(ss_r[p] + 1.f);
      const float4 oz0 = ((const float4*)(o_s0 + (size_t)t * 1024))[q];
      const float4 oz1 = ((const float4*)(o_s1 + (size_t)t * 1024))[q];
      const float4 oe0 = ((const float4*)(o_r0 + (size_t)p * 1024))[q];
      const float4 oe1 = ((const float4*)(o_r1 + (size_t)p * 1024))[q];
      const float4 c0s = ((const float4*)(w2c0_s))[q];
      const float4 c0r = ((const float4*)(w2c0_r + (size_t)e * 1024))[q];
      const bool last = (q == 255);      // n=1023 is padding
      const float ozf0 = oz0.x + oz1.x + tz * c0s.x;
      const float ozf1 = oz0.y + oz1.y + tz * c0s.y;
      const float ozf2 = oz0.z + oz1.z + tz * c0s.z;
      const float ozf3 = last ? 0.f : (oz0.w + oz1.w + tz * c0s.w);
      const float oef0 = oe0.x + oe1.x + tr * c0r.x;
      const float oef1 = oe0.y + oe1.y + tr * c0r.y;
      const float oef2 = oe0.z + oe1.z + tr * c0r.z;
      const float oef3 = last ? 0.f : (oe0.w + oe1.w + tr * c0r.w);
      const float tw = 2.f * wv;
      c0 = ozf0 + tw * oef0;
      c1 = ozf1 + tw * oef1;
      c2 = ozf2 + tw * oef2;
      c3 = ozf3 + tw * oef3;
      float sc = c0 * c0 + c1 * c1 + c2 * c2 + c3 * c3;
      float sz = ozf0 * ozf0 + ozf1 * ozf1 + ozf2 * ozf2 + ozf3 * ozf3;
      float sr = oef0 * oef0 + oef1 * oef1 + oef2 * oef2 + oef3 * oef3;
#pragma unroll
      for (int off = 32; off > 0; off >>= 1) {
        sc += __shfl_down(sc, off);
        sz += __shfl_down(sz, off);
        sr += __shfl_down(sr, off);
      }
      if (lane == 0) { rs2[grp][0][gw] = sc; rs2[grp][1][gw] = sz; rs2[grp][2][gw] = sr; }
    }
    __syncthreads();
    if (valid) {
      const float space2 = rs2[grp][0][0] + rs2[grp][0][1] + rs2[grp][0][2] + rs2[grp][0][3];
      const float ss_oz  = rs2[grp][1][0] + rs2[grp][1][1] + rs2[grp][1][2] + rs2[grp][1][3];
      const float ss_or  = rs2[grp][2][0] + rs2[grp][2][1] + rs2[grp][2][2] + rs2[grp][2][3];
      const float comb0 = sqrtf(ss_oz + 1.f) + 2.f + 2.f * wv * sqrtf(ss_or + 1.f);
      const float li = space2 - comb0 * comb0;
      const float inv = 1.f / sqrtf(fmaxf(fabsf(li), 1e-8f));
      float* orow = out + (size_t)t * 1024;
      const int j = 1 + q * 4;
      orow[j]     = c0 * inv;
      orow[j + 1] = c1 * inv;
      orow[j + 2] = c2 * inv;
      if (q != 255) orow[j + 3] = c3 * inv;
      if (q == 0) orow[0] = comb0 * inv;
    }
    __syncthreads();
  }
}

extern "C" void kernel_launch(void* const* d_in, const int* in_sizes, int n_in,
                              void* d_out, int out_size, void* d_ws, size_t ws_size,
                              hipStream_t stream) {
  const float* x      = (const float*)d_in[0];
  const float* gate_w = (const float*)d_in[1];
  const float* gate_b = (const float*)d_in[2];
  const float* W1     = (const float*)d_in[3];
  const float* W3     = (const float*)d_in[4];
  const float* W2     = (const float*)d_in[5];
  const float* Ws1    = (const float*)d_in[6];
  const float* Ws3    = (const float*)d_in[7];
  const float* Ws2    = (const float*)d_in[8];
  float* out = (float*)d_out;

  char* ws = (char*)d_ws;
  size_t off = 0;
  auto alloc = [&](size_t bytes) {
    void* p = ws + off;
    off += (bytes + 255) & ~(size_t)255;
    return p;
  };
  bf16*  x_bf = (bf16*) alloc((size_t)TOK * 1024 * 2);
  bf16*  h_r  = (bf16*) alloc((size_t)TOK * 1024 * 2);
  bf16*  h_s  = (bf16*) alloc((size_t)TOK * 1024 * 2);
  float* o_r0 = (float*)alloc((size_t)TOK * 1024 * 4);
  float* o_s0 = (float*)alloc((size_t)TOK * 1024 * 4);
  float* ss   = (float*)alloc((size_t)2 * TOK * 4);
  int*   eidx = (int*)  alloc((size_t)TOK * 4);
  float* ewgt = (float*)alloc((size_t)TOK * 4);
  int*   perm = (int*)  alloc((size_t)TOK * 4);
  int*   posf = (int*)  alloc((size_t)TOK * 4);
  int4*  wl1  = (int4*) alloc((size_t)SMAX * 16);
  int*   wn   = (int*)  alloc(32);
  unsigned* done2 = (unsigned*)alloc(32);
  float* w2c0_r = (float*)alloc((size_t)NE * 1024 * 4);   // padded [E][1024]
  float* w2c0_s = (float*)alloc((size_t)1024 * 4);
  bf16*  w13  = (bf16*) alloc((size_t)8 * 2046 * 1024 * 2);
  bf16*  ws13 = (bf16*) alloc((size_t)2046 * 1024 * 2);
  bf16*  w2b  = (bf16*) alloc((size_t)8 * 1023 * 1024 * 2);
  bf16*  ws2b = (bf16*) alloc((size_t)1023 * 1024 * 2);

  // split-K second-half buffers ALIAS the w13 region (w13 is dead after mlp1).
  float* o_r1 = (float*)w13;
  float* o_s1 = (float*)w13 + (size_t)TOK * 1024;

  float* ss_r  = ss;
  float* ss_z  = ss + TOK;

  // both MLP kernels use 128KB dynamic LDS (dbuf 256x64 A + 256x64 B)
  const int MLP_LDS = 2 * (256 * 64 + 256 * 64) * 2;  // 131072 B
  (void)hipFuncSetAttribute((const void*)mlp1_kernel,
                            hipFuncAttributeMaxDynamicSharedMemorySize, MLP_LDS);
  (void)hipFuncSetAttribute((const void*)mlp2_kernel,
                            hipFuncAttributeMaxDynamicSharedMemorySize, MLP_LDS);

  prep_kernel<<<GATEB + NCVT, 256, 0, stream>>>(
      x, gate_w, gate_b, W1, W3, W2, Ws1, Ws3, Ws2,
      x_bf, eidx, ewgt, ss, w13, ws13, w2b, ws2b, w2c0_r, w2c0_s, h_r, h_s);
  route_kernel<<<1, 256, 0, stream>>>(eidx, perm, posf, wl1, wn, done2);
  mlp1_kernel<<<8 * SMAX, 1024, MLP_LDS, stream>>>(x_bf, w13, ws13, perm, wl1, wn,
                                                   h_r, h_s, ss_r, ss_z);
  mlp2_kernel<<<GRID2, 1024, MLP_LDS, stream>>>(h_r, h_s, w2b, ws2b, wl1, wn,
                                                o_r0, o_r1, o_s0, o_s1,
                                                ss_r, ss_z, w2c0_r, w2c0_s,
                                                eidx, posf, ewgt, done2, out);
}

// Round 12
// 236.550 us; speedup vs baseline: 3.0460x; 1.0607x over previous
//
#include <hip/hip_runtime.h>

typedef __bf16 bf16;
typedef __attribute__((ext_vector_type(8))) __bf16 bf16x8;
typedef __attribute__((ext_vector_type(4))) float floatx4;

#define TOK 2048
#define DD  1024
#define NE  8
#define SMAX 24   // worklist slots (BM=256): <=15 routed + 8 shared, padded to %8==0

#define MFMA16(A,B,C) __builtin_amdgcn_mfma_f32_16x16x32_bf16(A,B,C,0,0,0)

__device__ __forceinline__ void load_lds16(const bf16* g, bf16* l) {
  __builtin_amdgcn_global_load_lds(
      (const __attribute__((address_space(1))) void*)g,
      (__attribute__((address_space(3))) void*)l, 16, 0, 0);
}

// fine-grained barrier: wait only the OLDEST outstanding loads, keep N in flight
#define WBAR(N) asm volatile("s_waitcnt vmcnt(" #N ")\n\ts_barrier" ::: "memory")
#define BARO    asm volatile("s_barrier" ::: "memory")

__device__ __forceinline__ uint4 pack_bf8(float4 a, float4 b) {
  union { bf16 h[8]; uint4 u; } p;
  p.h[0] = (bf16)a.x; p.h[1] = (bf16)a.y; p.h[2] = (bf16)a.z; p.h[3] = (bf16)a.w;
  p.h[4] = (bf16)b.x; p.h[5] = (bf16)b.y; p.h[6] = (bf16)b.z; p.h[7] = (bf16)b.w;
  return p.u;
}

// ---------------- prep: gate + x->bf16 + weight fp32->bf16 convert + w2col0 extract ----------------
// Gate blocks [0,2048): r7-verbatim. Convert: 2048 PERSISTENT blocks grid-striding 2 rows
// per iteration (8 floats/thread, uint4 16B stores). r7's one-tiny-block-per-row convert
// (4KB read / 2KB write each) ran at 2.4 TB/s — scheduling-granularity-bound; persistent
// striding blocks stream instead.
#define NCVT (8*2046 + 2046 + 8*1023 + 1023)
#define GATEB TOK
#define CVTB  2048
__global__ __launch_bounds__(256) void prep_kernel(
    const float* __restrict__ x, const float* __restrict__ gate_w,
    const float* __restrict__ gate_b,
    const float* __restrict__ W1, const float* __restrict__ W3,
    const float* __restrict__ W2, const float* __restrict__ Ws1,
    const float* __restrict__ Ws3, const float* __restrict__ Ws2,
    bf16* __restrict__ x_bf, int* __restrict__ eidx, float* __restrict__ ewgt,
    float* __restrict__ ss,
    bf16* __restrict__ w13, bf16* __restrict__ ws13,
    bf16* __restrict__ w2b, bf16* __restrict__ ws2b,
    float* __restrict__ w2c0_r, float* __restrict__ w2c0_s,
    bf16* __restrict__ h_r, bf16* __restrict__ h_s)
{
  const int bid = blockIdx.x, tid = threadIdx.x;

  if (bid >= GATEB) {
    // ---- weight convert: persistent blocks, 2 rows/iter, 8 floats/thread ----
    const int j0 = bid - GATEB;            // 0..CVTB-1
    const int tid2 = tid & 127;
#pragma unroll 1
    for (int r = j0 * 2 + (tid >> 7); r < NCVT; r += CVTB * 2) {
      const float* src; bf16* dst;
      float* c0dst = nullptr;
      if (r < 8 * 2046) {
        const int e = r / 2046, q = r % 2046;
        src = ((q & 1) ? W3 : W1) + ((size_t)e * 1023 + (q >> 1)) * 1024;
        dst = w13 + (size_t)r * 1024;
      } else if (r < 8 * 2046 + 2046) {
        const int q = r - 8 * 2046;
        src = ((q & 1) ? Ws3 : Ws1) + (size_t)(q >> 1) * 1024;
        dst = ws13 + (size_t)q * 1024;
      } else if (r < 8 * 2046 + 2046 + 8 * 1023) {
        const int q = r - (8 * 2046 + 2046);
        src = W2 + (size_t)q * 1024;
        dst = w2b + (size_t)q * 1024;
        c0dst = w2c0_r + (size_t)(q / 1023) * 1024 + (q % 1023);  // padded [E][1024]
      } else {
        const int q = r - (8 * 2046 + 2046 + 8 * 1023);
        src = Ws2 + (size_t)q * 1024;
        dst = ws2b + (size_t)q * 1024;
        c0dst = w2c0_s + q;
      }
      const float4 f0 = ((const float4*)src)[tid2 * 2];
      const float4 f1 = ((const float4*)src)[tid2 * 2 + 1];
      if (tid2 == 0 && c0dst) *c0dst = f0.x;   // W2[:,0] (time-lift column)
      ((uint4*)dst)[tid2] = pack_bf8(f0, f1);
    }
    return;
  }

  // ---- gate + x->bf16 + ss zero (ss_r, ss_z) + h[:,0]=0 ----
  const int t = bid;
  if (tid < 2) ss[tid * TOK + t] = 0.f;
  if (tid == 2) h_r[(size_t)t * 1024] = (bf16)0.f;
  if (tid == 3) h_s[(size_t)t * 1024] = (bf16)0.f;
  const float4 v = ((const float4*)(x + (size_t)t * DD))[tid];
  union { bf16 h[4]; uint2 u; } pk;
  pk.h[0] = (bf16)v.x; pk.h[1] = (bf16)v.y; pk.h[2] = (bf16)v.z; pk.h[3] = (bf16)v.w;
  ((uint2*)(x_bf + (size_t)t * DD))[tid] = pk.u;

  float acc[NE];
#pragma unroll
  for (int e = 0; e < NE; ++e) acc[e] = 0.f;
  const float vv[4] = {v.x, v.y, v.z, v.w};
#pragma unroll
  for (int i = 0; i < 4; ++i) {
    const int d = tid * 4 + i;
    if (d >= 1) {
#pragma unroll
      for (int e = 0; e < NE; ++e) acc[e] += vv[i] * gate_w[e * (DD - 1) + d - 1];
    }
  }
#pragma unroll
  for (int off = 32; off > 0; off >>= 1) {
#pragma unroll
    for (int e = 0; e < NE; ++e) acc[e] += __shfl_down(acc[e], off);
  }
  __shared__ float red[4][NE];
  const int wid = tid >> 6, lane = tid & 63;
  if (lane == 0) {
#pragma unroll
    for (int e = 0; e < NE; ++e) red[wid][e] = acc[e];
  }
  __syncthreads();
  if (tid == 0) {
    float lg[NE];
#pragma unroll
    for (int e = 0; e < NE; ++e) lg[e] = red[0][e] + red[1][e] + red[2][e] + red[3][e];
    float m = lg[0];
    for (int e = 1; e < NE; ++e) m = fmaxf(m, lg[e]);
    float ex[NE], s = 0.f;
    for (int e = 0; e < NE; ++e) { ex[e] = expf(lg[e] - m); s += ex[e]; }
    const float inv = 1.f / s;
    int best = 0; float bb = ex[0] * inv + gate_b[0];
    for (int e = 1; e < NE; ++e) {
      const float b = ex[e] * inv + gate_b[e];
      if (b > bb) { bb = b; best = e; }
    }
    eidx[t] = best;
    ewgt[t] = ex[best] * inv;
  }
}

// ---------------- routing: count + prefix + scatter + single BM=256 worklist ----------------
__global__ __launch_bounds__(256) void route_kernel(
    const int* __restrict__ eidx, int* __restrict__ perm,
    int* __restrict__ pos_of, int4* __restrict__ wl, int* __restrict__ n1)
{
  __shared__ int cnt[NE], off[NE], bas[NE + 1];
  const int tid = threadIdx.x;
  if (tid < NE) cnt[tid] = 0;
  __syncthreads();
  for (int t = tid; t < TOK; t += 256) atomicAdd(&cnt[eidx[t]], 1);
  __syncthreads();
  if (tid == 0) {
    int run = 0;
    for (int e = 0; e < NE; ++e) { bas[e] = run; off[e] = run; run += cnt[e]; }
    bas[NE] = run;
    int n = 0;
    for (int e = 0; e < NE; ++e)
      for (int r0 = 0; r0 < cnt[e]; r0 += 256) {
        int rows = cnt[e] - r0; if (rows > 256) rows = 256;
        wl[n++] = make_int4(bas[e] + r0, rows, e, 0);
      }
    for (int r0 = 0; r0 < TOK; r0 += 256) wl[n++] = make_int4(r0, 256, NE, 0);
    *n1 = n;
  }
  __syncthreads();
  for (int t = tid; t < TOK; t += 256) {
    const int e = eidx[t];
    const int p = atomicAdd(&off[e], 1);
    perm[p] = t;
    pos_of[t] = p;
  }
}

// ---------------- mlp1: BM=256 x BN=256 x BK=64, 16 waves, dbuf + vmcnt(4) ----------------
// UNCHANGED control (measured 44us, 0 conflicts, best per-CU staging rate).
__global__ __launch_bounds__(1024) void mlp1_kernel(
    const bf16* __restrict__ x_bf, const bf16* __restrict__ w13,
    const bf16* __restrict__ ws13,
    const int* __restrict__ perm, const int4* __restrict__ wl,
    const int* __restrict__ wl_n,
    bf16* __restrict__ h_r, bf16* __restrict__ h_s,
    float* __restrict__ ss_r, float* __restrict__ ss_z)
{
  const int bid = blockIdx.x;
  const int slot = bid % SMAX, nt = bid / SMAX;   // nt in 0..7
  if (slot >= *wl_n) return;
  const int4 wle = wl[slot];
  const int mbase = wle.x, rows = wle.y, eid = wle.z;
  const int tid = threadIdx.x;
  const bool routed = (eid < NE);
  const bf16* bmat = routed ? w13 + (size_t)eid * 2046 * 1024 : ws13;
  bf16* hbuf  = routed ? h_r : h_s;
  float* ssbuf = routed ? ss_r : ss_z;

  extern __shared__ __align__(16) bf16 smem[];
  bf16* const Asb[2] = {smem, smem + 16384};            // 256x64 each
  bf16* const Bsb[2] = {smem + 32768, smem + 49152};    // 256x64 each
  __shared__ int toks[256];
  if (tid < 256) {
    int r = tid < rows ? tid : rows - 1;
    toks[tid] = routed ? perm[mbase + r] : (mbase + r);
  }
  __syncthreads();

  const int wid = tid >> 6, lane = tid & 63;
  const int srow = lane >> 3;
  const int kbg  = (lane & 7) ^ (srow & 7);
  const bf16 *aG0, *aG1, *bG0, *bG1;
  int aL0o, aL1o, bL0o, bL1o;
  {
    const int r0 = wid * 16;
    aG0 = x_bf + (size_t)toks[r0 + 0 + srow] * 1024 + kbg * 8;
    aG1 = x_bf + (size_t)toks[r0 + 8 + srow] * 1024 + kbg * 8;
    aL0o = (r0 + 0) * 64; aL1o = (r0 + 8) * 64;
    int b0 = nt * 256 + r0 + 0 + srow; if (b0 > 2045) b0 = 2045;
    int b1 = nt * 256 + r0 + 8 + srow; if (b1 > 2045) b1 = 2045;
    bG0 = bmat + (size_t)b0 * 1024 + kbg * 8;
    bG1 = bmat + (size_t)b1 * 1024 + kbg * 8;
    bL0o = (r0 + 0) * 64; bL1o = (r0 + 8) * 64;
  }

  const int lrow = lane & 15, quad = lane >> 4, sw = lane & 7;
  const int wrow = (wid >> 2) * 64, wcol = (wid & 3) * 64;
  int aoff[4], boff[4], koff[2];
#pragma unroll
  for (int mi = 0; mi < 4; ++mi) aoff[mi] = (wrow + mi * 16 + lrow) * 64;
#pragma unroll
  for (int ni = 0; ni < 4; ++ni) boff[ni] = (wcol + ni * 16 + lrow) * 64;
#pragma unroll
  for (int kk = 0; kk < 2; ++kk) koff[kk] = ((kk * 4 + quad) ^ sw) * 8;

  const floatx4 fz = {0.f, 0.f, 0.f, 0.f};
  floatx4 acc[4][4];
#pragma unroll
  for (int mi = 0; mi < 4; ++mi)
#pragma unroll
    for (int ni = 0; ni < 4; ++ni) acc[mi][ni] = fz;

#define STAGE1(KE, BUF) { \
    load_lds16(aG0 + (KE), Asb[BUF] + aL0o); load_lds16(aG1 + (KE), Asb[BUF] + aL1o); \
    load_lds16(bG0 + (KE), Bsb[BUF] + bL0o); load_lds16(bG1 + (KE), Bsb[BUF] + bL1o); }

#define COMP1(BUF) { \
_Pragma("unroll") \
    for (int kk = 0; kk < 2; ++kk) { \
      bf16x8 av[4], bv[4]; \
_Pragma("unroll") \
      for (int mi = 0; mi < 4; ++mi) av[mi] = *(const bf16x8*)(Asb[BUF] + aoff[mi] + koff[kk]); \
_Pragma("unroll") \
      for (int ni = 0; ni < 4; ++ni) bv[ni] = *(const bf16x8*)(Bsb[BUF] + boff[ni] + koff[kk]); \
_Pragma("unroll") \
      for (int mi = 0; mi < 4; ++mi) \
_Pragma("unroll") \
        for (int ni = 0; ni < 4; ++ni) \
          acc[mi][ni] = MFMA16(av[mi], bv[ni], acc[mi][ni]); \
    } }

  STAGE1(0, 0)
  STAGE1(64, 1)
#pragma unroll 1
  for (int t = 0; t < 7; ++t) {
    const int ke = t * 128;
    WBAR(4); COMP1(0) BARO; STAGE1(ke + 128, 0)
    WBAR(4); COMP1(1) BARO; STAGE1(ke + 192, 1)
  }
  WBAR(4); COMP1(0)
  WBAR(0); COMP1(1)
#undef STAGE1
#undef COMP1

  // epilogue: interleaved cols -> (s1,s3) via lane^1 shuffle, gate, store h(bf16), sumsq
#pragma unroll
  for (int mi = 0; mi < 4; ++mi) {
#pragma unroll
    for (int r = 0; r < 4; ++r) {
      const int row = wrow + mi * 16 + quad * 4 + r;
      const bool rowok = row < rows;
      float ssum = 0.f;
#pragma unroll
      for (int ni = 0; ni < 4; ++ni) {
        const float c = acc[mi][ni][r];
        const float partner = __shfl_xor(c, 1);
        const float s1 = (lane & 1) ? partner : c;
        const float s3 = (lane & 1) ? c : partner;
        const float sp = (s1 / (1.f + __expf(-s1))) * s3;
        const int P = (nt * 256 + wcol + ni * 16 + lrow) >> 1;
        const bool ok = rowok && ((lane & 1) == 0) && (P < 1023);
        if (ok) hbuf[(size_t)(mbase + row) * 1024 + 1 + P] = (bf16)sp;
        ssum += ok ? sp * sp : 0.f;
      }
      ssum += __shfl_xor(ssum, 1);
      ssum += __shfl_xor(ssum, 2);
      ssum += __shfl_xor(ssum, 4);
      ssum += __shfl_xor(ssum, 8);
      if (lrow == 0 && rowok) atomicAdd(ssbuf + mbase + row, ssum);
    }
  }
}

// ---------------- mlp2: BM=256 x BN=256, SPLIT-K x2, dual-buffer plain stores ----------------
// kh=0 writes o_*0, kh=1 writes o_*1 (no atomics, no zero-init; combine sums halves).
// h[:,0] is zero so the MFMA contributes only the space part; combine adds t*W2[:,0].
__global__ __launch_bounds__(1024) void mlp2_kernel(
    const bf16* __restrict__ h_r, const bf16* __restrict__ h_s,
    const bf16* __restrict__ w2b, const bf16* __restrict__ ws2b,
    const int4* __restrict__ wl, const int* __restrict__ wl_n,
    float* __restrict__ o_r0, float* __restrict__ o_r1,
    float* __restrict__ o_s0, float* __restrict__ o_s1)
{
  const int bid = blockIdx.x;
  const int slot = bid % SMAX;
  const int rest = bid / SMAX;        // 0..7
  const int nt = rest & 3, kh = rest >> 2;
  if (slot >= *wl_n) return;
  const int4 wle = wl[slot];
  const int mbase = wle.x, rows = wle.y, eid = wle.z;
  const int tid = threadIdx.x;
  const bool routed = (eid < NE);
  const bf16* abuf = routed ? h_r : h_s;
  const bf16* bmat = routed ? w2b + (size_t)eid * 1023 * 1024 : ws2b;
  float* obuf = routed ? (kh ? o_r1 : o_r0) : (kh ? o_s1 : o_s0);
  const int n0 = nt * 256;
  const int kbase = kh * 512;

  extern __shared__ __align__(16) bf16 smem[];
  bf16* const Asb[2] = {smem, smem + 16384};            // 256x64 each
  bf16* const Bsb[2] = {smem + 32768, smem + 49152};    // 256x64 each

  const int wid = tid >> 6, lane = tid & 63;
  const int srow = lane >> 3;
  const int kbg  = (lane & 7) ^ (srow & 7);
  const bf16 *aG0, *aG1, *bG0, *bG1;
  int aL0o, aL1o, bL0o, bL1o;
  {
    const int r0 = wid * 16;
    int ra0 = r0 + 0 + srow; if (ra0 >= rows) ra0 = rows - 1;
    int ra1 = r0 + 8 + srow; if (ra1 >= rows) ra1 = rows - 1;
    aG0 = abuf + (size_t)(mbase + ra0) * 1024 + kbase + kbg * 8;
    aG1 = abuf + (size_t)(mbase + ra1) * 1024 + kbase + kbg * 8;
    aL0o = (r0 + 0) * 64; aL1o = (r0 + 8) * 64;
    int b0 = n0 + r0 + 0 + srow; if (b0 > 1022) b0 = 1022;
    int b1 = n0 + r0 + 8 + srow; if (b1 > 1022) b1 = 1022;
    bG0 = bmat + (size_t)b0 * 1024 + kbase + kbg * 8;
    bG1 = bmat + (size_t)b1 * 1024 + kbase + kbg * 8;
    bL0o = (r0 + 0) * 64; bL1o = (r0 + 8) * 64;
  }

  const int lrow = lane & 15, quad = lane >> 4, sw = lane & 7;
  const int wrow = (wid >> 2) * 64, wcol = (wid & 3) * 64;
  int aoff[4], boff[4], koff[2];
#pragma unroll
  for (int mi = 0; mi < 4; ++mi) aoff[mi] = (wrow + mi * 16 + lrow) * 64;
#pragma unroll
  for (int ni = 0; ni < 4; ++ni) boff[ni] = (wcol + ni * 16 + lrow) * 64;
#pragma unroll
  for (int kk = 0; kk < 2; ++kk) koff[kk] = ((kk * 4 + quad) ^ sw) * 8;

  const floatx4 fz = {0.f, 0.f, 0.f, 0.f};
  floatx4 acc[4][4];
#pragma unroll
  for (int mi = 0; mi < 4; ++mi)
#pragma unroll
    for (int ni = 0; ni < 4; ++ni) acc[mi][ni] = fz;

#define STAGE2(KE, BUF) { \
    load_lds16(aG0 + (KE), Asb[BUF] + aL0o); load_lds16(aG1 + (KE), Asb[BUF] + aL1o); \
    load_lds16(bG0 + (KE), Bsb[BUF] + bL0o); load_lds16(bG1 + (KE), Bsb[BUF] + bL1o); }

#define COMP2(BUF) { \
_Pragma("unroll") \
    for (int kk = 0; kk < 2; ++kk) { \
      bf16x8 av[4], bv[4]; \
_Pragma("unroll") \
      for (int mi = 0; mi < 4; ++mi) av[mi] = *(const bf16x8*)(Asb[BUF] + aoff[mi] + koff[kk]); \
_Pragma("unroll") \
      for (int ni = 0; ni < 4; ++ni) bv[ni] = *(const bf16x8*)(Bsb[BUF] + boff[ni] + koff[kk]); \
_Pragma("unroll") \
      for (int mi = 0; mi < 4; ++mi) \
_Pragma("unroll") \
        for (int ni = 0; ni < 4; ++ni) \
          acc[mi][ni] = MFMA16(av[mi], bv[ni], acc[mi][ni]); \
    } }

  // 8 K-steps (this block's half of K)
  STAGE2(0, 0)
  STAGE2(64, 1)
#pragma unroll 1
  for (int t = 0; t < 3; ++t) {
    const int ke = t * 128;
    WBAR(4); COMP2(0) BARO; STAGE2(ke + 128, 0)
    WBAR(4); COMP2(1) BARO; STAGE2(ke + 192, 1)
  }
  WBAR(4); COMP2(0)
  WBAR(0); COMP2(1)
#undef STAGE2
#undef COMP2

  // epilogue: plain fp32 stores into this kh's buffer
#pragma unroll
  for (int mi = 0; mi < 4; ++mi) {
#pragma unroll
    for (int r = 0; r < 4; ++r) {
      const int row = wrow + mi * 16 + quad * 4 + r;
      if (row < rows) {
        float* orow = obuf + (size_t)(mbase + row) * 1024;
#pragma unroll
        for (int ni = 0; ni < 4; ++ni) {
          const int n = n0 + wcol + ni * 16 + lrow;
          if (n < 1023) orow[n] = acc[mi][ni][r];
        }
      }
    }
  }
}

// ---------------- final: sum split-K halves + t*W2col0 + LResNet combine + normalize ----------------
__global__ __launch_bounds__(256) void combine_kernel(
    const float* __restrict__ o_r0, const float* __restrict__ o_r1,
    const float* __restrict__ o_s0, const float* __restrict__ o_s1,
    const float* __restrict__ ss_r, const float* __restrict__ ss_z,
    const float* __restrict__ w2c0_r, const float* __restrict__ w2c0_s,
    const int* __restrict__ eidx, const int* __restrict__ pos_of,
    const float* __restrict__ wgt, float* __restrict__ out)
{
  const int t = blockIdx.x, tid = threadIdx.x;
  const int p = pos_of[t];
  const int e = eidx[t];
  const float w = wgt[t];
  const float tz = sqrtf(ss_z[t] + 1.f);   // shared-expert mid time
  const float tr = sqrtf(ss_r[p] + 1.f);   // routed-expert mid time
  const float4 oz0 = ((const float4*)(o_s0 + (size_t)t * 1024))[tid];
  const float4 oz1 = ((const float4*)(o_s1 + (size_t)t * 1024))[tid];
  const float4 oe0 = ((const float4*)(o_r0 + (size_t)p * 1024))[tid];
  const float4 oe1 = ((const float4*)(o_r1 + (size_t)p * 1024))[tid];
  const float4 c0s = ((const float4*)(w2c0_s))[tid];
  const float4 c0r = ((const float4*)(w2c0_r + (size_t)e * 1024))[tid];
  const bool last = (tid == 255);          // n=1023 is padding
  float ozf0 = oz0.x + oz1.x + tz * c0s.x;
  float ozf1 = oz0.y + oz1.y + tz * c0s.y;
  float ozf2 = oz0.z + oz1.z + tz * c0s.z;
  float ozf3 = last ? 0.f : (oz0.w + oz1.w + tz * c0s.w);
  float oef0 = oe0.x + oe1.x + tr * c0r.x;
  float oef1 = oe0.y + oe1.y + tr * c0r.y;
  float oef2 = oe0.z + oe1.z + tr * c0r.z;
  float oef3 = last ? 0.f : (oe0.w + oe1.w + tr * c0r.w);
  const float tw = 2.f * w;
  const float c0 = ozf0 + tw * oef0;
  const float c1 = ozf1 + tw * oef1;
  const float c2 = ozf2 + tw * oef2;
  const float c3 = ozf3 + tw * oef3;
  float sc = c0 * c0 + c1 * c1 + c2 * c2 + c3 * c3;
  float sz = ozf0 * ozf0 + ozf1 * ozf1 + ozf2 * ozf2 + ozf3 * ozf3;
  float sr = oef0 * oef0 + oef1 * oef1 + oef2 * oef2 + oef3 * oef3;
#pragma unroll
  for (int off = 32; off > 0; off >>= 1) {
    sc += __shfl_down(sc, off);
    sz += __shfl_down(sz, off);
    sr += __shfl_down(sr, off);
  }
  __shared__ float rs[3][4];
  if ((tid & 63) == 0) {
    rs[0][tid >> 6] = sc; rs[1][tid >> 6] = sz; rs[2][tid >> 6] = sr;
  }
  __syncthreads();
  const float space2 = rs[0][0] + rs[0][1] + rs[0][2] + rs[0][3];
  const float ss_oz  = rs[1][0] + rs[1][1] + rs[1][2] + rs[1][3];
  const float ss_or  = rs[2][0] + rs[2][1] + rs[2][2] + rs[2][3];
  const float comb0 = sqrtf(ss_oz + 1.f) + 2.f + 2.f * w * sqrtf(ss_or + 1.f);
  const float li = space2 - comb0 * comb0;
  const float inv = 1.f / sqrtf(fmaxf(fabsf(li), 1e-8f));
  float* orow = out + (size_t)t * 1024;
  const int j = 1 + tid * 4;
  orow[j]     = c0 * inv;
  orow[j + 1] = c1 * inv;
  orow[j + 2] = c2 * inv;
  if (!last) orow[j + 3] = c3 * inv;
  if (tid == 0) orow[0] = comb0 * inv;
}

extern "C" void kernel_launch(void* const* d_in, const int* in_sizes, int n_in,
                              void* d_out, int out_size, void* d_ws, size_t ws_size,
                              hipStream_t stream) {
  const float* x      = (const float*)d_in[0];
  const float* gate_w = (const float*)d_in[1];
  const float* gate_b = (const float*)d_in[2];
  const float* W1     = (const float*)d_in[3];
  const float* W3     = (const float*)d_in[4];
  const float* W2     = (const float*)d_in[5];
  const float* Ws1    = (const float*)d_in[6];
  const float* Ws3    = (const float*)d_in[7];
  const float* Ws2    = (const float*)d_in[8];
  float* out = (float*)d_out;

  char* ws = (char*)d_ws;
  size_t off = 0;
  auto alloc = [&](size_t bytes) {
    void* p = ws + off;
    off += (bytes + 255) & ~(size_t)255;
    return p;
  };
  bf16*  x_bf = (bf16*) alloc((size_t)TOK * 1024 * 2);
  bf16*  h_r  = (bf16*) alloc((size_t)TOK * 1024 * 2);
  bf16*  h_s  = (bf16*) alloc((size_t)TOK * 1024 * 2);
  float* o_r0 = (float*)alloc((size_t)TOK * 1024 * 4);
  float* o_s0 = (float*)alloc((size_t)TOK * 1024 * 4);
  float* ss   = (float*)alloc((size_t)2 * TOK * 4);
  int*   eidx = (int*)  alloc((size_t)TOK * 4);
  float* ewgt = (float*)alloc((size_t)TOK * 4);
  int*   perm = (int*)  alloc((size_t)TOK * 4);
  int*   posf = (int*)  alloc((size_t)TOK * 4);
  int4*  wl1  = (int4*) alloc((size_t)SMAX * 16);
  int*   wn   = (int*)  alloc(32);
  float* w2c0_r = (float*)alloc((size_t)NE * 1024 * 4);   // padded [E][1024]
  float* w2c0_s = (float*)alloc((size_t)1024 * 4);
  bf16*  w13  = (bf16*) alloc((size_t)8 * 2046 * 1024 * 2);
  bf16*  ws13 = (bf16*) alloc((size_t)2046 * 1024 * 2);
  bf16*  w2b  = (bf16*) alloc((size_t)8 * 1023 * 1024 * 2);
  bf16*  ws2b = (bf16*) alloc((size_t)1023 * 1024 * 2);

  // split-K second-half buffers ALIAS the w13 region (w13 is dead after mlp1;
  // mlp2's writes are stream-ordered after mlp1 completes; next iteration's prep
  // rewrites w13 only after this iteration's combine consumed o_*1).
  float* o_r1 = (float*)w13;
  float* o_s1 = (float*)w13 + (size_t)TOK * 1024;

  float* ss_r  = ss;
  float* ss_z  = ss + TOK;

  // both MLP kernels use 128KB dynamic LDS (dbuf 256x64 A + 256x64 B)
  const int MLP_LDS = 2 * (256 * 64 + 256 * 64) * 2;  // 131072 B
  (void)hipFuncSetAttribute((const void*)mlp1_kernel,
                            hipFuncAttributeMaxDynamicSharedMemorySize, MLP_LDS);
  (void)hipFuncSetAttribute((const void*)mlp2_kernel,
                            hipFuncAttributeMaxDynamicSharedMemorySize, MLP_LDS);

  prep_kernel<<<GATEB + CVTB, 256, 0, stream>>>(
      x, gate_w, gate_b, W1, W3, W2, Ws1, Ws3, Ws2,
      x_bf, eidx, ewgt, ss, w13, ws13, w2b, ws2b, w2c0_r, w2c0_s, h_r, h_s);
  route_kernel<<<1, 256, 0, stream>>>(eidx, perm, posf, wl1, wn);
  mlp1_kernel<<<8 * SMAX, 1024, MLP_LDS, stream>>>(x_bf, w13, ws13, perm, wl1, wn,
                                                   h_r, h_s, ss_r, ss_z);
  mlp2_kernel<<<8 * SMAX, 1024, MLP_LDS, stream>>>(h_r, h_s, w2b, ws2b, wl1, wn,
                                                   o_r0, o_r1, o_s0, o_s1);
  combine_kernel<<<TOK, 256, 0, stream>>>(o_r0, o_r1, o_s0, o_s1, ss_r, ss_z,
                                          w2c0_r, w2c0_s, eidx, posf, ewgt, out);
}

// Round 13
// 235.913 us; speedup vs baseline: 3.0542x; 1.0027x over previous
//
#include <hip/hip_runtime.h>

typedef __bf16 bf16;
typedef __attribute__((ext_vector_type(8))) __bf16 bf16x8;
typedef __attribute__((ext_vector_type(4))) float floatx4;

#define TOK 2048
#define DD  1024
#define NE  8
#define SMAX 24   // worklist slots (BM=256): <=15 routed + 8 shared, padded to %8==0

#define MFMA16(A,B,C) __builtin_amdgcn_mfma_f32_16x16x32_bf16(A,B,C,0,0,0)

__device__ __forceinline__ void load_lds16(const bf16* g, bf16* l) {
  __builtin_amdgcn_global_load_lds(
      (const __attribute__((address_space(1))) void*)g,
      (__attribute__((address_space(3))) void*)l, 16, 0, 0);
}

// fine-grained barrier: wait only the OLDEST outstanding loads, keep N in flight
#define WBAR(N) asm volatile("s_waitcnt vmcnt(" #N ")\n\ts_barrier" ::: "memory")
#define BARO    asm volatile("s_barrier" ::: "memory")

__device__ __forceinline__ uint4 pack_bf8(float4 a, float4 b) {
  union { bf16 h[8]; uint4 u; } p;
  p.h[0] = (bf16)a.x; p.h[1] = (bf16)a.y; p.h[2] = (bf16)a.z; p.h[3] = (bf16)a.w;
  p.h[4] = (bf16)b.x; p.h[5] = (bf16)b.y; p.h[6] = (bf16)b.z; p.h[7] = (bf16)b.w;
  return p.u;
}

// ---------------- prep: gate + x->bf16 + weight fp32->bf16 convert + w2col0 extract ----------------
// Gate blocks [0,2048): r7-verbatim. Convert: 2048 persistent blocks grid-striding 2 rows
// per iteration, MANUALLY SOFTWARE-PIPELINED 2-deep: iteration i+1's float4 loads are
// issued BEFORE iteration i's uint4 store, hiding HBM read latency under the store stream
// (the old `unroll 1` serial load->pack->store chain couldn't overlap across iterations).
#define NCVT (8*2046 + 2046 + 8*1023 + 1023)
#define GATEB TOK
#define CVTB  2048
__global__ __launch_bounds__(256) void prep_kernel(
    const float* __restrict__ x, const float* __restrict__ gate_w,
    const float* __restrict__ gate_b,
    const float* __restrict__ W1, const float* __restrict__ W3,
    const float* __restrict__ W2, const float* __restrict__ Ws1,
    const float* __restrict__ Ws3, const float* __restrict__ Ws2,
    bf16* __restrict__ x_bf, int* __restrict__ eidx, float* __restrict__ ewgt,
    float* __restrict__ ss,
    bf16* __restrict__ w13, bf16* __restrict__ ws13,
    bf16* __restrict__ w2b, bf16* __restrict__ ws2b,
    float* __restrict__ w2c0_r, float* __restrict__ w2c0_s,
    bf16* __restrict__ h_r, bf16* __restrict__ h_s)
{
  const int bid = blockIdx.x, tid = threadIdx.x;

  if (bid >= GATEB) {
    // ---- weight convert: persistent blocks, 2 rows/iter, 2-deep pipelined ----
    const int tid2 = tid & 127;
    auto resolve = [&](int rr, const float*& src, bf16*& dst, float*& c0dst) {
      c0dst = nullptr;
      if (rr < 8 * 2046) {
        const int e = rr / 2046, q = rr % 2046;
        src = ((q & 1) ? W3 : W1) + ((size_t)e * 1023 + (q >> 1)) * 1024;
        dst = w13 + (size_t)rr * 1024;
      } else if (rr < 8 * 2046 + 2046) {
        const int q = rr - 8 * 2046;
        src = ((q & 1) ? Ws3 : Ws1) + (size_t)(q >> 1) * 1024;
        dst = ws13 + (size_t)q * 1024;
      } else if (rr < 8 * 2046 + 2046 + 8 * 1023) {
        const int q = rr - (8 * 2046 + 2046);
        src = W2 + (size_t)q * 1024;
        dst = w2b + (size_t)q * 1024;
        c0dst = w2c0_r + (size_t)(q / 1023) * 1024 + (q % 1023);  // padded [E][1024]
      } else {
        const int q = rr - (8 * 2046 + 2046 + 8 * 1023);
        src = Ws2 + (size_t)q * 1024;
        dst = ws2b + (size_t)q * 1024;
        c0dst = w2c0_s + q;
      }
    };
    int r = (bid - GATEB) * 2 + (tid >> 7);          // < 4096 <= NCVT always
    const float* src; bf16* dst; float* c0dst;
    resolve(r, src, dst, c0dst);
    float4 f0 = ((const float4*)src)[tid2 * 2];
    float4 f1 = ((const float4*)src)[tid2 * 2 + 1];
#pragma unroll 1
    for (;;) {
      const int rn = r + CVTB * 2;
      if (rn < NCVT) {
        const float* src2; bf16* dst2; float* c0dst2;
        resolve(rn, src2, dst2, c0dst2);
        const float4 g0 = ((const float4*)src2)[tid2 * 2];   // issue next loads
        const float4 g1 = ((const float4*)src2)[tid2 * 2 + 1];
        if (tid2 == 0 && c0dst) *c0dst = f0.x;               // W2[:,0] time-lift col
        ((uint4*)dst)[tid2] = pack_bf8(f0, f1);              // store current
        f0 = g0; f1 = g1; dst = dst2; c0dst = c0dst2; r = rn;
      } else {
        if (tid2 == 0 && c0dst) *c0dst = f0.x;
        ((uint4*)dst)[tid2] = pack_bf8(f0, f1);
        break;
      }
    }
    return;
  }

  // ---- gate + x->bf16 + ss zero (ss_r, ss_z) + h[:,0]=0 ----
  const int t = bid;
  if (tid < 2) ss[tid * TOK + t] = 0.f;
  if (tid == 2) h_r[(size_t)t * 1024] = (bf16)0.f;
  if (tid == 3) h_s[(size_t)t * 1024] = (bf16)0.f;
  const float4 v = ((const float4*)(x + (size_t)t * DD))[tid];
  union { bf16 h[4]; uint2 u; } pk;
  pk.h[0] = (bf16)v.x; pk.h[1] = (bf16)v.y; pk.h[2] = (bf16)v.z; pk.h[3] = (bf16)v.w;
  ((uint2*)(x_bf + (size_t)t * DD))[tid] = pk.u;

  float acc[NE];
#pragma unroll
  for (int e = 0; e < NE; ++e) acc[e] = 0.f;
  const float vv[4] = {v.x, v.y, v.z, v.w};
#pragma unroll
  for (int i = 0; i < 4; ++i) {
    const int d = tid * 4 + i;
    if (d >= 1) {
#pragma unroll
      for (int e = 0; e < NE; ++e) acc[e] += vv[i] * gate_w[e * (DD - 1) + d - 1];
    }
  }
#pragma unroll
  for (int off = 32; off > 0; off >>= 1) {
#pragma unroll
    for (int e = 0; e < NE; ++e) acc[e] += __shfl_down(acc[e], off);
  }
  __shared__ float red[4][NE];
  const int wid = tid >> 6, lane = tid & 63;
  if (lane == 0) {
#pragma unroll
    for (int e = 0; e < NE; ++e) red[wid][e] = acc[e];
  }
  __syncthreads();
  if (tid == 0) {
    float lg[NE];
#pragma unroll
    for (int e = 0; e < NE; ++e) lg[e] = red[0][e] + red[1][e] + red[2][e] + red[3][e];
    float m = lg[0];
    for (int e = 1; e < NE; ++e) m = fmaxf(m, lg[e]);
    float ex[NE], s = 0.f;
    for (int e = 0; e < NE; ++e) { ex[e] = expf(lg[e] - m); s += ex[e]; }
    const float inv = 1.f / s;
    int best = 0; float bb = ex[0] * inv + gate_b[0];
    for (int e = 1; e < NE; ++e) {
      const float b = ex[e] * inv + gate_b[e];
      if (b > bb) { bb = b; best = e; }
    }
    eidx[t] = best;
    ewgt[t] = ex[best] * inv;
  }
}

// ---------------- routing: count + prefix + scatter + single BM=256 worklist ----------------
__global__ __launch_bounds__(256) void route_kernel(
    const int* __restrict__ eidx, int* __restrict__ perm,
    int* __restrict__ pos_of, int4* __restrict__ wl, int* __restrict__ n1)
{
  __shared__ int cnt[NE], off[NE], bas[NE + 1];
  const int tid = threadIdx.x;
  if (tid < NE) cnt[tid] = 0;
  __syncthreads();
  for (int t = tid; t < TOK; t += 256) atomicAdd(&cnt[eidx[t]], 1);
  __syncthreads();
  if (tid == 0) {
    int run = 0;
    for (int e = 0; e < NE; ++e) { bas[e] = run; off[e] = run; run += cnt[e]; }
    bas[NE] = run;
    int n = 0;
    for (int e = 0; e < NE; ++e)
      for (int r0 = 0; r0 < cnt[e]; r0 += 256) {
        int rows = cnt[e] - r0; if (rows > 256) rows = 256;
        wl[n++] = make_int4(bas[e] + r0, rows, e, 0);
      }
    for (int r0 = 0; r0 < TOK; r0 += 256) wl[n++] = make_int4(r0, 256, NE, 0);
    *n1 = n;
  }
  __syncthreads();
  for (int t = tid; t < TOK; t += 256) {
    const int e = eidx[t];
    const int p = atomicAdd(&off[e], 1);
    perm[p] = t;
    pos_of[t] = p;
  }
}

// ---------------- mlp1: BM=256 x BN=256 x BK=64, 16 waves, dbuf + vmcnt(4) ----------------
// UNCHANGED control (measured 44us fast-container / 62us slow, 0 conflicts).
__global__ __launch_bounds__(1024) void mlp1_kernel(
    const bf16* __restrict__ x_bf, const bf16* __restrict__ w13,
    const bf16* __restrict__ ws13,
    const int* __restrict__ perm, const int4* __restrict__ wl,
    const int* __restrict__ wl_n,
    bf16* __restrict__ h_r, bf16* __restrict__ h_s,
    float* __restrict__ ss_r, float* __restrict__ ss_z)
{
  const int bid = blockIdx.x;
  const int slot = bid % SMAX, nt = bid / SMAX;   // nt in 0..7
  if (slot >= *wl_n) return;
  const int4 wle = wl[slot];
  const int mbase = wle.x, rows = wle.y, eid = wle.z;
  const int tid = threadIdx.x;
  const bool routed = (eid < NE);
  const bf16* bmat = routed ? w13 + (size_t)eid * 2046 * 1024 : ws13;
  bf16* hbuf  = routed ? h_r : h_s;
  float* ssbuf = routed ? ss_r : ss_z;

  extern __shared__ __align__(16) bf16 smem[];
  bf16* const Asb[2] = {smem, smem + 16384};            // 256x64 each
  bf16* const Bsb[2] = {smem + 32768, smem + 49152};    // 256x64 each
  __shared__ int toks[256];
  if (tid < 256) {
    int r = tid < rows ? tid : rows - 1;
    toks[tid] = routed ? perm[mbase + r] : (mbase + r);
  }
  __syncthreads();

  const int wid = tid >> 6, lane = tid & 63;
  const int srow = lane >> 3;
  const int kbg  = (lane & 7) ^ (srow & 7);
  const bf16 *aG0, *aG1, *bG0, *bG1;
  int aL0o, aL1o, bL0o, bL1o;
  {
    const int r0 = wid * 16;
    aG0 = x_bf + (size_t)toks[r0 + 0 + srow] * 1024 + kbg * 8;
    aG1 = x_bf + (size_t)toks[r0 + 8 + srow] * 1024 + kbg * 8;
    aL0o = (r0 + 0) * 64; aL1o = (r0 + 8) * 64;
    int b0 = nt * 256 + r0 + 0 + srow; if (b0 > 2045) b0 = 2045;
    int b1 = nt * 256 + r0 + 8 + srow; if (b1 > 2045) b1 = 2045;
    bG0 = bmat + (size_t)b0 * 1024 + kbg * 8;
    bG1 = bmat + (size_t)b1 * 1024 + kbg * 8;
    bL0o = (r0 + 0) * 64; bL1o = (r0 + 8) * 64;
  }

  const int lrow = lane & 15, quad = lane >> 4, sw = lane & 7;
  const int wrow = (wid >> 2) * 64, wcol = (wid & 3) * 64;
  int aoff[4], boff[4], koff[2];
#pragma unroll
  for (int mi = 0; mi < 4; ++mi) aoff[mi] = (wrow + mi * 16 + lrow) * 64;
#pragma unroll
  for (int ni = 0; ni < 4; ++ni) boff[ni] = (wcol + ni * 16 + lrow) * 64;
#pragma unroll
  for (int kk = 0; kk < 2; ++kk) koff[kk] = ((kk * 4 + quad) ^ sw) * 8;

  const floatx4 fz = {0.f, 0.f, 0.f, 0.f};
  floatx4 acc[4][4];
#pragma unroll
  for (int mi = 0; mi < 4; ++mi)
#pragma unroll
    for (int ni = 0; ni < 4; ++ni) acc[mi][ni] = fz;

#define STAGE1(KE, BUF) { \
    load_lds16(aG0 + (KE), Asb[BUF] + aL0o); load_lds16(aG1 + (KE), Asb[BUF] + aL1o); \
    load_lds16(bG0 + (KE), Bsb[BUF] + bL0o); load_lds16(bG1 + (KE), Bsb[BUF] + bL1o); }

#define COMP1(BUF) { \
_Pragma("unroll") \
    for (int kk = 0; kk < 2; ++kk) { \
      bf16x8 av[4], bv[4]; \
_Pragma("unroll") \
      for (int mi = 0; mi < 4; ++mi) av[mi] = *(const bf16x8*)(Asb[BUF] + aoff[mi] + koff[kk]); \
_Pragma("unroll") \
      for (int ni = 0; ni < 4; ++ni) bv[ni] = *(const bf16x8*)(Bsb[BUF] + boff[ni] + koff[kk]); \
_Pragma("unroll") \
      for (int mi = 0; mi < 4; ++mi) \
_Pragma("unroll") \
        for (int ni = 0; ni < 4; ++ni) \
          acc[mi][ni] = MFMA16(av[mi], bv[ni], acc[mi][ni]); \
    } }

  STAGE1(0, 0)
  STAGE1(64, 1)
#pragma unroll 1
  for (int t = 0; t < 7; ++t) {
    const int ke = t * 128;
    WBAR(4); COMP1(0) BARO; STAGE1(ke + 128, 0)
    WBAR(4); COMP1(1) BARO; STAGE1(ke + 192, 1)
  }
  WBAR(4); COMP1(0)
  WBAR(0); COMP1(1)
#undef STAGE1
#undef COMP1

  // epilogue: interleaved cols -> (s1,s3) via lane^1 shuffle, gate, store h(bf16), sumsq
#pragma unroll
  for (int mi = 0; mi < 4; ++mi) {
#pragma unroll
    for (int r = 0; r < 4; ++r) {
      const int row = wrow + mi * 16 + quad * 4 + r;
      const bool rowok = row < rows;
      float ssum = 0.f;
#pragma unroll
      for (int ni = 0; ni < 4; ++ni) {
        const float c = acc[mi][ni][r];
        const float partner = __shfl_xor(c, 1);
        const float s1 = (lane & 1) ? partner : c;
        const float s3 = (lane & 1) ? c : partner;
        const float sp = (s1 / (1.f + __expf(-s1))) * s3;
        const int P = (nt * 256 + wcol + ni * 16 + lrow) >> 1;
        const bool ok = rowok && ((lane & 1) == 0) && (P < 1023);
        if (ok) hbuf[(size_t)(mbase + row) * 1024 + 1 + P] = (bf16)sp;
        ssum += ok ? sp * sp : 0.f;
      }
      ssum += __shfl_xor(ssum, 1);
      ssum += __shfl_xor(ssum, 2);
      ssum += __shfl_xor(ssum, 4);
      ssum += __shfl_xor(ssum, 8);
      if (lrow == 0 && rowok) atomicAdd(ssbuf + mbase + row, ssum);
    }
  }
}

// ---------------- mlp2: BM=256 x BN=256, SPLIT-K x2, dual-buffer plain stores ----------------
// kh=0 writes o_*0, kh=1 writes o_*1 (no atomics, no zero-init; combine sums halves).
// h[:,0] is zero so the MFMA contributes only the space part; combine adds t*W2[:,0].
__global__ __launch_bounds__(1024) void mlp2_kernel(
    const bf16* __restrict__ h_r, const bf16* __restrict__ h_s,
    const bf16* __restrict__ w2b, const bf16* __restrict__ ws2b,
    const int4* __restrict__ wl, const int* __restrict__ wl_n,
    float* __restrict__ o_r0, float* __restrict__ o_r1,
    float* __restrict__ o_s0, float* __restrict__ o_s1)
{
  const int bid = blockIdx.x;
  const int slot = bid % SMAX;
  const int rest = bid / SMAX;        // 0..7
  const int nt = rest & 3, kh = rest >> 2;
  if (slot >= *wl_n) return;
  const int4 wle = wl[slot];
  const int mbase = wle.x, rows = wle.y, eid = wle.z;
  const int tid = threadIdx.x;
  const bool routed = (eid < NE);
  const bf16* abuf = routed ? h_r : h_s;
  const bf16* bmat = routed ? w2b + (size_t)eid * 1023 * 1024 : ws2b;
  float* obuf = routed ? (kh ? o_r1 : o_r0) : (kh ? o_s1 : o_s0);
  const int n0 = nt * 256;
  const int kbase = kh * 512;

  extern __shared__ __align__(16) bf16 smem[];
  bf16* const Asb[2] = {smem, smem + 16384};            // 256x64 each
  bf16* const Bsb[2] = {smem + 32768, smem + 49152};    // 256x64 each

  const int wid = tid >> 6, lane = tid & 63;
  const int srow = lane >> 3;
  const int kbg  = (lane & 7) ^ (srow & 7);
  const bf16 *aG0, *aG1, *bG0, *bG1;
  int aL0o, aL1o, bL0o, bL1o;
  {
    const int r0 = wid * 16;
    int ra0 = r0 + 0 + srow; if (ra0 >= rows) ra0 = rows - 1;
    int ra1 = r0 + 8 + srow; if (ra1 >= rows) ra1 = rows - 1;
    aG0 = abuf + (size_t)(mbase + ra0) * 1024 + kbase + kbg * 8;
    aG1 = abuf + (size_t)(mbase + ra1) * 1024 + kbase + kbg * 8;
    aL0o = (r0 + 0) * 64; aL1o = (r0 + 8) * 64;
    int b0 = n0 + r0 + 0 + srow; if (b0 > 1022) b0 = 1022;
    int b1 = n0 + r0 + 8 + srow; if (b1 > 1022) b1 = 1022;
    bG0 = bmat + (size_t)b0 * 1024 + kbase + kbg * 8;
    bG1 = bmat + (size_t)b1 * 1024 + kbase + kbg * 8;
    bL0o = (r0 + 0) * 64; bL1o = (r0 + 8) * 64;
  }

  const int lrow = lane & 15, quad = lane >> 4, sw = lane & 7;
  const int wrow = (wid >> 2) * 64, wcol = (wid & 3) * 64;
  int aoff[4], boff[4], koff[2];
#pragma unroll
  for (int mi = 0; mi < 4; ++mi) aoff[mi] = (wrow + mi * 16 + lrow) * 64;
#pragma unroll
  for (int ni = 0; ni < 4; ++ni) boff[ni] = (wcol + ni * 16 + lrow) * 64;
#pragma unroll
  for (int kk = 0; kk < 2; ++kk) koff[kk] = ((kk * 4 + quad) ^ sw) * 8;

  const floatx4 fz = {0.f, 0.f, 0.f, 0.f};
  floatx4 acc[4][4];
#pragma unroll
  for (int mi = 0; mi < 4; ++mi)
#pragma unroll
    for (int ni = 0; ni < 4; ++ni) acc[mi][ni] = fz;

#define STAGE2(KE, BUF) { \
    load_lds16(aG0 + (KE), Asb[BUF] + aL0o); load_lds16(aG1 + (KE), Asb[BUF] + aL1o); \
    load_lds16(bG0 + (KE), Bsb[BUF] + bL0o); load_lds16(bG1 + (KE), Bsb[BUF] + bL1o); }

#define COMP2(BUF) { \
_Pragma("unroll") \
    for (int kk = 0; kk < 2; ++kk) { \
      bf16x8 av[4], bv[4]; \
_Pragma("unroll") \
      for (int mi = 0; mi < 4; ++mi) av[mi] = *(const bf16x8*)(Asb[BUF] + aoff[mi] + koff[kk]); \
_Pragma("unroll") \
      for (int ni = 0; ni < 4; ++ni) bv[ni] = *(const bf16x8*)(Bsb[BUF] + boff[ni] + koff[kk]); \
_Pragma("unroll") \
      for (int mi = 0; mi < 4; ++mi) \
_Pragma("unroll") \
        for (int ni = 0; ni < 4; ++ni) \
          acc[mi][ni] = MFMA16(av[mi], bv[ni], acc[mi][ni]); \
    } }

  // 8 K-steps (this block's half of K)
  STAGE2(0, 0)
  STAGE2(64, 1)
#pragma unroll 1
  for (int t = 0; t < 3; ++t) {
    const int ke = t * 128;
    WBAR(4); COMP2(0) BARO; STAGE2(ke + 128, 0)
    WBAR(4); COMP2(1) BARO; STAGE2(ke + 192, 1)
  }
  WBAR(4); COMP2(0)
  WBAR(0); COMP2(1)
#undef STAGE2
#undef COMP2

  // epilogue: plain fp32 stores into this kh's buffer
#pragma unroll
  for (int mi = 0; mi < 4; ++mi) {
#pragma unroll
    for (int r = 0; r < 4; ++r) {
      const int row = wrow + mi * 16 + quad * 4 + r;
      if (row < rows) {
        float* orow = obuf + (size_t)(mbase + row) * 1024;
#pragma unroll
        for (int ni = 0; ni < 4; ++ni) {
          const int n = n0 + wcol + ni * 16 + lrow;
          if (n < 1023) orow[n] = acc[mi][ni][r];
        }
      }
    }
  }
}

// ---------------- final: sum split-K halves + t*W2col0 + LResNet combine + normalize ----------------
__global__ __launch_bounds__(256) void combine_kernel(
    const float* __restrict__ o_r0, const float* __restrict__ o_r1,
    const float* __restrict__ o_s0, const float* __restrict__ o_s1,
    const float* __restrict__ ss_r, const float* __restrict__ ss_z,
    const float* __restrict__ w2c0_r, const float* __restrict__ w2c0_s,
    const int* __restrict__ eidx, const int* __restrict__ pos_of,
    const float* __restrict__ wgt, float* __restrict__ out)
{
  const int t = blockIdx.x, tid = threadIdx.x;
  const int p = pos_of[t];
  const int e = eidx[t];
  const float w = wgt[t];
  const float tz = sqrtf(ss_z[t] + 1.f);   // shared-expert mid time
  const float tr = sqrtf(ss_r[p] + 1.f);   // routed-expert mid time
  const float4 oz0 = ((const float4*)(o_s0 + (size_t)t * 1024))[tid];
  const float4 oz1 = ((const float4*)(o_s1 + (size_t)t * 1024))[tid];
  const float4 oe0 = ((const float4*)(o_r0 + (size_t)p * 1024))[tid];
  const float4 oe1 = ((const float4*)(o_r1 + (size_t)p * 1024))[tid];
  const float4 c0s = ((const float4*)(w2c0_s))[tid];
  const float4 c0r = ((const float4*)(w2c0_r + (size_t)e * 1024))[tid];
  const bool last = (tid == 255);          // n=1023 is padding
  float ozf0 = oz0.x + oz1.x + tz * c0s.x;
  float ozf1 = oz0.y + oz1.y + tz * c0s.y;
  float ozf2 = oz0.z + oz1.z + tz * c0s.z;
  float ozf3 = last ? 0.f : (oz0.w + oz1.w + tz * c0s.w);
  float oef0 = oe0.x + oe1.x + tr * c0r.x;
  float oef1 = oe0.y + oe1.y + tr * c0r.y;
  float oef2 = oe0.z + oe1.z + tr * c0r.z;
  float oef3 = last ? 0.f : (oe0.w + oe1.w + tr * c0r.w);
  const float tw = 2.f * w;
  const float c0 = ozf0 + tw * oef0;
  const float c1 = ozf1 + tw * oef1;
  const float c2 = ozf2 + tw * oef2;
  const float c3 = ozf3 + tw * oef3;
  float sc = c0 * c0 + c1 * c1 + c2 * c2 + c3 * c3;
  float sz = ozf0 * ozf0 + ozf1 * ozf1 + ozf2 * ozf2 + ozf3 * ozf3;
  float sr = oef0 * oef0 + oef1 * oef1 + oef2 * oef2 + oef3 * oef3;
#pragma unroll
  for (int off = 32; off > 0; off >>= 1) {
    sc += __shfl_down(sc, off);
    sz += __shfl_down(sz, off);
    sr += __shfl_down(sr, off);
  }
  __shared__ float rs[3][4];
  if ((tid & 63) == 0) {
    rs[0][tid >> 6] = sc; rs[1][tid >> 6] = sz; rs[2][tid >> 6] = sr;
  }
  __syncthreads();
  const float space2 = rs[0][0] + rs[0][1] + rs[0][2] + rs[0][3];
  const float ss_oz  = rs[1][0] + rs[1][1] + rs[1][2] + rs[1][3];
  const float ss_or  = rs[2][0] + rs[2][1] + rs[2][2] + rs[2][3];
  const float comb0 = sqrtf(ss_oz + 1.f) + 2.f + 2.f * w * sqrtf(ss_or + 1.f);
  const float li = space2 - comb0 * comb0;
  const float inv = 1.f / sqrtf(fmaxf(fabsf(li), 1e-8f));
  float* orow = out + (size_t)t * 1024;
  const int j = 1 + tid * 4;
  orow[j]     = c0 * inv;
  orow[j + 1] = c1 * inv;
  orow[j + 2] = c2 * inv;
  if (!last) orow[j + 3] = c3 * inv;
  if (tid == 0) orow[0] = comb0 * inv;
}

extern "C" void kernel_launch(void* const* d_in, const int* in_sizes, int n_in,
                              void* d_out, int out_size, void* d_ws, size_t ws_size,
                              hipStream_t stream) {
  const float* x      = (const float*)d_in[0];
  const float* gate_w = (const float*)d_in[1];
  const float* gate_b = (const float*)d_in[2];
  const float* W1     = (const float*)d_in[3];
  const float* W3     = (const float*)d_in[4];
  const float* W2     = (const float*)d_in[5];
  const float* Ws1    = (const float*)d_in[6];
  const float* Ws3    = (const float*)d_in[7];
  const float* Ws2    = (const float*)d_in[8];
  float* out = (float*)d_out;

  char* ws = (char*)d_ws;
  size_t off = 0;
  auto alloc = [&](size_t bytes) {
    void* p = ws + off;
    off += (bytes + 255) & ~(size_t)255;
    return p;
  };
  bf16*  x_bf = (bf16*) alloc((size_t)TOK * 1024 * 2);
  bf16*  h_r  = (bf16*) alloc((size_t)TOK * 1024 * 2);
  bf16*  h_s  = (bf16*) alloc((size_t)TOK * 1024 * 2);
  float* o_r0 = (float*)alloc((size_t)TOK * 1024 * 4);
  float* o_s0 = (float*)alloc((size_t)TOK * 1024 * 4);
  float* ss   = (float*)alloc((size_t)2 * TOK * 4);
  int*   eidx = (int*)  alloc((size_t)TOK * 4);
  float* ewgt = (float*)alloc((size_t)TOK * 4);
  int*   perm = (int*)  alloc((size_t)TOK * 4);
  int*   posf = (int*)  alloc((size_t)TOK * 4);
  int4*  wl1  = (int4*) alloc((size_t)SMAX * 16);
  int*   wn   = (int*)  alloc(32);
  float* w2c0_r = (float*)alloc((size_t)NE * 1024 * 4);   // padded [E][1024]
  float* w2c0_s = (float*)alloc((size_t)1024 * 4);
  bf16*  w13  = (bf16*) alloc((size_t)8 * 2046 * 1024 * 2);
  bf16*  ws13 = (bf16*) alloc((size_t)2046 * 1024 * 2);
  bf16*  w2b  = (bf16*) alloc((size_t)8 * 1023 * 1024 * 2);
  bf16*  ws2b = (bf16*) alloc((size_t)1023 * 1024 * 2);

  // split-K second-half buffers ALIAS the w13 region (w13 is dead after mlp1;
  // mlp2's writes are stream-ordered after mlp1 completes; next iteration's prep
  // rewrites w13 only after this iteration's combine consumed o_*1).
  float* o_r1 = (float*)w13;
  float* o_s1 = (float*)w13 + (size_t)TOK * 1024;

  float* ss_r  = ss;
  float* ss_z  = ss + TOK;

  // both MLP kernels use 128KB dynamic LDS (dbuf 256x64 A + 256x64 B)
  const int MLP_LDS = 2 * (256 * 64 + 256 * 64) * 2;  // 131072 B
  (void)hipFuncSetAttribute((const void*)mlp1_kernel,
                            hipFuncAttributeMaxDynamicSharedMemorySize, MLP_LDS);
  (void)hipFuncSetAttribute((const void*)mlp2_kernel,
                            hipFuncAttributeMaxDynamicSharedMemorySize, MLP_LDS);

  prep_kernel<<<GATEB + CVTB, 256, 0, stream>>>(
      x, gate_w, gate_b, W1, W3, W2, Ws1, Ws3, Ws2,
      x_bf, eidx, ewgt, ss, w13, ws13, w2b, ws2b, w2c0_r, w2c0_s, h_r, h_s);
  route_kernel<<<1, 256, 0, stream>>>(eidx, perm, posf, wl1, wn);
  mlp1_kernel<<<8 * SMAX, 1024, MLP_LDS, stream>>>(x_bf, w13, ws13, perm, wl1, wn,
                                                   h_r, h_s, ss_r, ss_z);
  mlp2_kernel<<<8 * SMAX, 1024, MLP_LDS, stream>>>(h_r, h_s, w2b, ws2b, wl1, wn,
                                                   o_r0, o_r1, o_s0, o_s1);
  combine_kernel<<<TOK, 256, 0, stream>>>(o_r0, o_r1, o_s0, o_s1, ss_r, ss_z,
                                          w2c0_r, w2c0_s, eidx, posf, ewgt, out);
}